// Round 1
// baseline (6313.080 us; speedup 1.0000x reference)
//
#include <hip/hip_runtime.h>
#include <stdint.h>

#define CONF_T 0.05f
#define NMS_T  0.5f

// ---- workspace layout (float offsets) ----
#define OFF_T3   0u           // 256x6400  (pre-smooth p3 input / reg-chain ping)
#define OFF_T4   1638400u     // 256x1600
#define OFF_T5   2048000u     // 256x400
#define OFF_P3   2150400u     // FPN outputs
#define OFF_P4   3788800u
#define OFF_P5   4198400u
#define OFF_HA3  4300800u     // cls-chain ping
#define OFF_HA4  5939200u
#define OFF_HA5  6348800u
#define OFF_HB3  6451200u     // cls-chain pong (final cls feats)
#define OFF_HB4  8089600u
#define OFF_HB5  8499200u
#define OFF_HD3  8601600u     // reg-chain pong (final reg feats)
#define OFF_HD4  10240000u
#define OFF_HD5  10649600u
#define OFF_CLS  10752000u    // 80x8400 logits
#define OFF_REG  11424000u    // 4x8400
#define OFF_CTN  11457600u    // 8400
#define OFF_KEYS 11466000u    // 16384 x uint64 (32768 float slots)

// ---------------- conv 1x1 (+ optional nearest-up2 add) ----------------
// out[co][outBase+p] = sum_ci w[co*Cin+ci]*in[ci*NPX+p] + b[co] (+ add up2)
// tile 64 px x 64 co; 256 thr: pxg=t&31 (2 px each), cg=t>>5 (8 co each)
__launch_bounds__(256)
__global__ void conv1x1_kernel(const float* __restrict__ in, const float* __restrict__ w,
                               const float* __restrict__ b, float* __restrict__ out,
                               const float* __restrict__ add,
                               int Cin, int Cout, int NPX, int W, int outStride, int outBase)
{
    __shared__ float s_in[16][64];
    __shared__ float s_w[16][64];
    int t = threadIdx.x;
    int pxg = t & 31, cg = t >> 5;
    int px0 = blockIdx.x * 64;
    int co0 = blockIdx.y * 64;
    float acc[8][2];
#pragma unroll
    for (int c = 0; c < 8; ++c) { acc[c][0] = 0.f; acc[c][1] = 0.f; }
    int chunks = Cin >> 4;
    int wco = t >> 2, wpart = t & 3;
    for (int ch = 0; ch < chunks; ++ch) {
        int ci0 = ch << 4;
#pragma unroll
        for (int k = 0; k < 4; ++k) {
            int id = t + k * 256;
            int ci = id >> 6, pp = id & 63;
            int gp = px0 + pp;
            s_in[ci][pp] = (gp < NPX) ? in[(size_t)(ci0 + ci) * NPX + gp] : 0.f;
        }
        {
            int gco = co0 + wco;
            if (gco < Cout) {
                const float* run = w + (size_t)gco * Cin + ci0;
#pragma unroll
                for (int k = 0; k < 4; ++k) {
                    int e = wpart + 4 * k;
                    s_w[e][wco] = run[e];
                }
            } else {
#pragma unroll
                for (int k = 0; k < 4; ++k) s_w[wpart + 4 * k][wco] = 0.f;
            }
        }
        __syncthreads();
#pragma unroll
        for (int ci = 0; ci < 16; ++ci) {
            float i0 = s_in[ci][pxg * 2], i1 = s_in[ci][pxg * 2 + 1];
#pragma unroll
            for (int c = 0; c < 8; ++c) {
                float wv = s_w[ci][cg * 8 + c];
                acc[c][0] += wv * i0;
                acc[c][1] += wv * i1;
            }
        }
        __syncthreads();
    }
    for (int c = 0; c < 8; ++c) {
        int co = co0 + cg * 8 + c;
        if (co >= Cout) break;
        float bb = b[co];
#pragma unroll
        for (int j = 0; j < 2; ++j) {
            int p = px0 + pxg * 2 + j;
            if (p < NPX) {
                float v = acc[c][j] + bb;
                if (add) {
                    int y = p / W, x = p % W;
                    int Sp = W >> 1;
                    v += add[(size_t)co * (Sp * Sp) + (y >> 1) * Sp + (x >> 1)];
                }
                out[(size_t)co * outStride + outBase + p] = v;
            }
        }
    }
}

// ---------------- conv 3x3, Cin=Cout=256, pad 1 ----------------
// templated tile: TW x TH spatial, TCO out-channels; 256 threads.
// blockIdx.z selects branch (A/B) so cls & reg head chains run in one launch.
template<int TW, int TH, int TCO>
__launch_bounds__(256)
__global__ void conv3x3_t(const float* __restrict__ srcA, const float* __restrict__ srcB,
                          const float* __restrict__ wA, const float* __restrict__ wB,
                          const float* __restrict__ bA, const float* __restrict__ bB,
                          float* __restrict__ dstA, float* __restrict__ dstB,
                          int H, int W, int act)
{
    constexpr int TPX  = TW * TH;
    constexpr int NXQ  = TW / 4;
    constexpr int PXGN = TPX / 4;
    constexpr int COG  = 256 / PXGN;
    constexpr int COPT = TCO / COG;
    constexpr int INW  = TW + 4;       // padded LDS row stride (16B aligned)
    constexpr int INH  = TH + 2;
    constexpr int INSLOTS = 8 * INH * (TW + 2);
    constexpr int PARTS = 256 / TCO;
    constexpr int EPT   = 72 / PARTS;

    __shared__ float s_in[8][INH][INW];
    __shared__ float s_w[8][9][TCO];

    const float* src = srcA; const float* w = wA; const float* bias = bA; float* dst = dstA;
    if (blockIdx.z == 1) { src = srcB; w = wB; bias = bB; dst = dstB; }

    int t = threadIdx.x;
    int pxg = t % PXGN, cg = t / PXGN;
    int xq = pxg % NXQ, yr = pxg / NXQ;
    int x0 = xq * 4;
    int nTx = (W + TW - 1) / TW;
    int tx = blockIdx.x % nTx, ty = blockIdx.x / nTx;
    int bx0 = tx * TW, by0 = ty * TH;
    int co0 = blockIdx.y * TCO;
    int HW = H * W;

    float acc[COPT][4];
#pragma unroll
    for (int c = 0; c < COPT; ++c)
#pragma unroll
        for (int i = 0; i < 4; ++i) acc[c][i] = 0.f;

    int wco = t / PARTS;   // 0..TCO-1
    int wpart = t % PARTS;
    const float* wrunbase = w + (size_t)(co0 + wco) * 256 * 9;

    for (int ch = 0; ch < 32; ++ch) {
        int ci0 = ch * 8;
        // stage input tile (zero-padded borders)
#pragma unroll
        for (int k = 0; k * 256 < INSLOTS; ++k) {
            int id = t + k * 256;
            if (id < INSLOTS) {
                int ci = id / (INH * (TW + 2));
                int rem = id % (INH * (TW + 2));
                int r = rem / (TW + 2), cc = rem % (TW + 2);
                int gy = by0 - 1 + r, gx = bx0 - 1 + cc;
                float v = 0.f;
                if (gy >= 0 && gy < H && gx >= 0 && gx < W)
                    v = src[(size_t)(ci0 + ci) * HW + gy * W + gx];
                s_in[ci][r][cc] = v;
            }
        }
        // stage weights -> [ci][tap][co]
        {
            const float* run = wrunbase + (size_t)ci0 * 9;
#pragma unroll
            for (int k = 0; k < EPT; ++k) {
                int e = wpart + PARTS * k;     // 0..71
                int ci = e / 9, tap = e % 9;
                s_w[ci][tap][wco] = run[e];
            }
        }
        __syncthreads();
        for (int ci = 0; ci < 8; ++ci) {
            float inr[3][6];
#pragma unroll
            for (int ky = 0; ky < 3; ++ky)
#pragma unroll
                for (int j = 0; j < 6; ++j)
                    inr[ky][j] = s_in[ci][yr + ky][x0 + j];
#pragma unroll
            for (int ky = 0; ky < 3; ++ky) {
#pragma unroll
                for (int kx = 0; kx < 3; ++kx) {
#pragma unroll
                    for (int c = 0; c < COPT; ++c) {
                        float wv = s_w[ci][ky * 3 + kx][cg * COPT + c];
#pragma unroll
                        for (int i = 0; i < 4; ++i)
                            acc[c][i] += wv * inr[ky][kx + i];
                    }
                }
            }
        }
        __syncthreads();
    }
    int y = by0 + yr;
#pragma unroll
    for (int c = 0; c < COPT; ++c) {
        int co = co0 + cg * COPT + c;
        float bb = bias[co];
#pragma unroll
        for (int i = 0; i < 4; ++i) {
            int x = bx0 + x0 + i;
            if (x < W && y < H) {
                float v = acc[c][i] + bb;
                if (act) v = (v >= 0.f) ? v : 0.1f * v;
                dst[(size_t)co * HW + y * W + x] = v;
            }
        }
    }
}

// ---------------- decode: scores, argmax, boxes, sort keys ----------------
__launch_bounds__(256)
__global__ void decode_kernel(const float* __restrict__ cls, const float* __restrict__ reg,
                              const float* __restrict__ ctn, float* __restrict__ out,
                              unsigned long long* __restrict__ keys)
{
    int p = blockIdx.x * 256 + threadIdx.x;
    if (p >= 16384) return;
    if (p >= 8400) { keys[p] = ~0ull; return; }
    int base, hs; float s;
    if (p < 6400)      { base = 0;    hs = 80; s = 8.f;  }
    else if (p < 8000) { base = 6400; hs = 40; s = 16.f; }
    else               { base = 8000; hs = 20; s = 32.f; }
    int local = p - base;
    float gx = (float)(local % hs), gy = (float)(local / hs);
    float ct = ctn[p];
    float sct = 1.f / (1.f + expf(-ct));
    float best = -1.f; int arg = 0;
    for (int c = 0; c < 80; ++c) {
        float v = cls[(size_t)c * 8400 + p];
        float sv = 1.f / (1.f + expf(-v));
        float sc = sqrtf(sv * sct);
        if (sc > best) { best = sc; arg = c; }
    }
    float r0 = reg[0 * 8400 + p], r1 = reg[1 * 8400 + p];
    float r2 = reg[2 * 8400 + p], r3 = reg[3 * 8400 + p];
    float x1 = (gx - expf(r0)) * s / 640.f;
    float y1 = (gy - expf(r1)) * s / 640.f;
    float x2 = (gx + expf(r2)) * s / 640.f;
    float y2 = (gy + expf(r3)) * s / 640.f;
    x1 = fminf(fmaxf(x1, 0.f), 1.f);
    y1 = fminf(fmaxf(y1, 0.f), 1.f);
    x2 = fminf(fmaxf(x2, 0.f), 1.f);
    y2 = fminf(fmaxf(y2, 0.f), 1.f);
    out[p * 4 + 0] = x1; out[p * 4 + 1] = y1;
    out[p * 4 + 2] = x2; out[p * 4 + 3] = y2;
    out[33600 + p] = best;
    out[42000 + p] = (float)arg;
    out[50400 + p] = 0.f;     // keep init
    unsigned int ub = __float_as_uint(best);   // best >= 0 -> order-preserving bits
    keys[p] = ((unsigned long long)(~ub) << 32) | (unsigned int)p;  // asc sort = desc score, stable
}

// ---------------- single-block bitonic sort of 16384 uint64 keys ----------------
__launch_bounds__(1024)
__global__ void sort_kernel(unsigned long long* __restrict__ keys)
{
    int t = threadIdx.x;
    for (unsigned k = 2; k <= 16384u; k <<= 1) {
        for (unsigned j = k >> 1; j > 0; j >>= 1) {
            for (int m = 0; m < 16; ++m) {
                unsigned i = (unsigned)t + m * 1024u;
                unsigned ixj = i ^ j;
                if (ixj > i) {
                    unsigned long long a = keys[i], bb = keys[ixj];
                    bool up = ((i & k) == 0);
                    if ((a > bb) == up) { keys[i] = bb; keys[ixj] = a; }
                }
            }
            __syncthreads();
        }
    }
}

// ---------------- per-class greedy NMS (1 block per class) ----------------
#define MAXK 2048
__launch_bounds__(256)
__global__ void nms_kernel(const unsigned long long* __restrict__ keys,
                           const float* __restrict__ outbuf, float* __restrict__ keep)
{
    int c = blockIdx.x;
    int t = threadIdx.x;
    __shared__ float sx1[256], sy1[256], sx2[256], sy2[256], ssc[256];
    __shared__ int scls[256], sidx[256];
    __shared__ float kx1[MAXK], ky1[MAXK], kx2[MAXK], ky2[MAXK], kar[MAXK];
    __shared__ int kcount;
    if (t == 0) kcount = 0;
    __syncthreads();
    const float* bb = outbuf;             // boxes at p*4
    const float* clsf = outbuf + 42000;   // class ids as float
    bool done = false;
    for (int wst = 0; wst < 16384 && !done; wst += 256) {
        unsigned long long key = keys[wst + t];
        unsigned int ub = ~(unsigned int)(key >> 32);
        float sc = __uint_as_float(ub);
        int idx = (int)(key & 0xffffffffu);
        int cl = -1;
        float x1 = 0.f, y1 = 0.f, x2 = 0.f, y2 = 0.f;
        if (sc >= CONF_T) {
            cl = (int)clsf[idx];
            x1 = bb[idx * 4 + 0]; y1 = bb[idx * 4 + 1];
            x2 = bb[idx * 4 + 2]; y2 = bb[idx * 4 + 3];
        }
        ssc[t] = sc; scls[t] = cl; sidx[t] = idx;
        sx1[t] = x1; sy1[t] = y1; sx2[t] = x2; sy2[t] = y2;
        __syncthreads();
        for (int e = 0; e < 256; ++e) {
            float sc_e = ssc[e];
            if (sc_e < CONF_T) { done = true; break; }   // sorted: rest below conf
            if (scls[e] != c) continue;
            float cx1 = sx1[e], cy1 = sy1[e], cx2 = sx2[e], cy2 = sy2[e];
            float carea = (cx2 - cx1) * (cy2 - cy1);
            int nk = kcount;
            int sup = 0;
            for (int bse = 0; bse < nk; bse += 256) {
                int j = bse + t;
                int f = 0;
                if (j < nk) {
                    float xx1 = fmaxf(cx1, kx1[j]);
                    float yy1 = fmaxf(cy1, ky1[j]);
                    float xx2 = fminf(cx2, kx2[j]);
                    float yy2 = fminf(cy2, ky2[j]);
                    float ww = fmaxf(1e-28f, xx2 - xx1);
                    float hh = fmaxf(1e-28f, yy2 - yy1);
                    float inter = ww * hh;
                    float ovr = inter / (kar[j] + carea - inter);
                    f = (ovr > NMS_T) ? 1 : 0;
                }
                sup |= __syncthreads_or(f);
                if (sup) break;
            }
            if (!sup) {
                if (t == 0) {
                    int kc = kcount;
                    if (kc < MAXK) {
                        kx1[kc] = cx1; ky1[kc] = cy1; kx2[kc] = cx2; ky2[kc] = cy2;
                        kar[kc] = carea;
                        kcount = kc + 1;
                    }
                    keep[sidx[e]] = 1.0f;
                }
                __syncthreads();
            }
        }
        __syncthreads();
    }
}

// ---------------- host orchestration ----------------
extern "C" void kernel_launch(void* const* d_in, const int* in_sizes, int n_in,
                              void* d_out, int out_size, void* d_ws, size_t ws_size,
                              hipStream_t stream)
{
    const float* c3      = (const float*)d_in[0];   // batch0 = first 128*6400
    const float* c4      = (const float*)d_in[1];
    const float* c5      = (const float*)d_in[2];
    const float* lat1_w  = (const float*)d_in[3];
    const float* lat1_b  = (const float*)d_in[4];
    const float* lat2_w  = (const float*)d_in[5];
    const float* lat2_b  = (const float*)d_in[6];
    const float* lat3_w  = (const float*)d_in[7];
    const float* lat3_b  = (const float*)d_in[8];
    const float* sm1_w   = (const float*)d_in[9];
    const float* sm1_b   = (const float*)d_in[10];
    const float* sm2_w   = (const float*)d_in[11];
    const float* sm2_b   = (const float*)d_in[12];
    const float* sm3_w   = (const float*)d_in[13];
    const float* sm3_b   = (const float*)d_in[14];
    const float* clsh_w  = (const float*)d_in[15];
    const float* clsh_b  = (const float*)d_in[16];
    const float* regh_w  = (const float*)d_in[17];
    const float* regh_b  = (const float*)d_in[18];
    const float* clsd_w  = (const float*)d_in[19];
    const float* clsd_b  = (const float*)d_in[20];
    const float* regd_w  = (const float*)d_in[21];
    const float* regd_b  = (const float*)d_in[22];
    const float* ctnd_w  = (const float*)d_in[23];
    const float* ctnd_b  = (const float*)d_in[24];

    float* ws = (float*)d_ws;
    float* T3 = ws + OFF_T3;  float* T4 = ws + OFF_T4;  float* T5 = ws + OFF_T5;
    float* P3 = ws + OFF_P3;  float* P4 = ws + OFF_P4;  float* P5 = ws + OFF_P5;
    float* HA3 = ws + OFF_HA3; float* HA4 = ws + OFF_HA4; float* HA5 = ws + OFF_HA5;
    float* HB3 = ws + OFF_HB3; float* HB4 = ws + OFF_HB4; float* HB5 = ws + OFF_HB5;
    float* HD3 = ws + OFF_HD3; float* HD4 = ws + OFF_HD4; float* HD5 = ws + OFF_HD5;
    float* CLS = ws + OFF_CLS; float* REG = ws + OFF_REG; float* CTN = ws + OFF_CTN;
    unsigned long long* KEYS = (unsigned long long*)(ws + OFF_KEYS);

    float* out = (float*)d_out;
    dim3 blk(256);
    const size_t WSTEP = 256u * 256u * 9u;   // per-head-layer weight stride

    // ---- FPN ----
    conv1x1_kernel<<<dim3(7, 4), blk, 0, stream>>>(c5, lat3_w, lat3_b, T5, nullptr,
                                                   512, 256, 400, 20, 400, 0);
    conv3x3_t<8, 4, 32><<<dim3(15, 8, 1), blk, 0, stream>>>(T5, T5, sm3_w, sm3_w, sm3_b, sm3_b,
                                                            P5, P5, 20, 20, 0);
    conv1x1_kernel<<<dim3(25, 4), blk, 0, stream>>>(c4, lat2_w, lat2_b, T4, T5,
                                                    256, 256, 1600, 40, 1600, 0);
    conv3x3_t<16, 4, 32><<<dim3(30, 8, 1), blk, 0, stream>>>(T4, T4, sm2_w, sm2_w, sm2_b, sm2_b,
                                                             P4, P4, 40, 40, 0);
    conv1x1_kernel<<<dim3(100, 4), blk, 0, stream>>>(c3, lat1_w, lat1_b, T3, T4,
                                                     128, 256, 6400, 80, 6400, 0);
    conv3x3_t<16, 8, 64><<<dim3(50, 4, 1), blk, 0, stream>>>(T3, T3, sm1_w, sm1_w, sm1_b, sm1_b,
                                                             P3, P3, 80, 80, 0);

    // ---- heads: per level, 4 layers, cls(A) + reg(B) merged by blockIdx.z ----
    // L3 (80x80)
    {
        float* ping[2][5] = { {P3, HA3, HB3, HA3, HB3},   // cls chain src->dst per layer
                              {P3, T3,  HD3, T3,  HD3} }; // reg chain
        for (int i = 0; i < 4; ++i) {
            conv3x3_t<16, 8, 64><<<dim3(50, 4, 2), blk, 0, stream>>>(
                ping[0][i], ping[1][i],
                clsh_w + (size_t)i * WSTEP, regh_w + (size_t)i * WSTEP,
                clsh_b + i * 256, regh_b + i * 256,
                ping[0][i + 1], ping[1][i + 1], 80, 80, 1);
        }
        conv1x1_kernel<<<dim3(100, 2), blk, 0, stream>>>(HB3, clsd_w, clsd_b, CLS, nullptr,
                                                         256, 80, 6400, 80, 8400, 0);
        conv1x1_kernel<<<dim3(100, 1), blk, 0, stream>>>(HD3, regd_w, regd_b, REG, nullptr,
                                                         256, 4, 6400, 80, 8400, 0);
        conv1x1_kernel<<<dim3(100, 1), blk, 0, stream>>>(HD3, ctnd_w, ctnd_b, CTN, nullptr,
                                                         256, 1, 6400, 80, 8400, 0);
    }
    // L4 (40x40)
    {
        float* ping[2][5] = { {P4, HA4, HB4, HA4, HB4},
                              {P4, T4,  HD4, T4,  HD4} };
        for (int i = 0; i < 4; ++i) {
            conv3x3_t<16, 4, 32><<<dim3(30, 8, 2), blk, 0, stream>>>(
                ping[0][i], ping[1][i],
                clsh_w + (size_t)i * WSTEP, regh_w + (size_t)i * WSTEP,
                clsh_b + i * 256, regh_b + i * 256,
                ping[0][i + 1], ping[1][i + 1], 40, 40, 1);
        }
        conv1x1_kernel<<<dim3(25, 2), blk, 0, stream>>>(HB4, clsd_w, clsd_b, CLS, nullptr,
                                                        256, 80, 1600, 40, 8400, 6400);
        conv1x1_kernel<<<dim3(25, 1), blk, 0, stream>>>(HD4, regd_w, regd_b, REG, nullptr,
                                                        256, 4, 1600, 40, 8400, 6400);
        conv1x1_kernel<<<dim3(25, 1), blk, 0, stream>>>(HD4, ctnd_w, ctnd_b, CTN, nullptr,
                                                        256, 1, 1600, 40, 8400, 6400);
    }
    // L5 (20x20)
    {
        float* ping[2][5] = { {P5, HA5, HB5, HA5, HB5},
                              {P5, T5,  HD5, T5,  HD5} };
        for (int i = 0; i < 4; ++i) {
            conv3x3_t<8, 4, 32><<<dim3(15, 8, 2), blk, 0, stream>>>(
                ping[0][i], ping[1][i],
                clsh_w + (size_t)i * WSTEP, regh_w + (size_t)i * WSTEP,
                clsh_b + i * 256, regh_b + i * 256,
                ping[0][i + 1], ping[1][i + 1], 20, 20, 1);
        }
        conv1x1_kernel<<<dim3(7, 2), blk, 0, stream>>>(HB5, clsd_w, clsd_b, CLS, nullptr,
                                                       256, 80, 400, 20, 8400, 8000);
        conv1x1_kernel<<<dim3(7, 1), blk, 0, stream>>>(HD5, regd_w, regd_b, REG, nullptr,
                                                       256, 4, 400, 20, 8400, 8000);
        conv1x1_kernel<<<dim3(7, 1), blk, 0, stream>>>(HD5, ctnd_w, ctnd_b, CTN, nullptr,
                                                       256, 1, 400, 20, 8400, 8000);
    }

    // ---- decode / sort / NMS ----
    decode_kernel<<<dim3(64), blk, 0, stream>>>(CLS, REG, CTN, out, KEYS);
    sort_kernel<<<dim3(1), dim3(1024), 0, stream>>>(KEYS);
    nms_kernel<<<dim3(80), blk, 0, stream>>>(KEYS, out, out + 50400);
}

// Round 2
// 4203.502 us; speedup vs baseline: 1.5019x; 1.5019x over previous
//
#include <hip/hip_runtime.h>
#include <stdint.h>

#define CONF_T 0.05f
#define NMS_T  0.5f

// ---- workspace layout (float offsets) ----
#define OFF_T3   0u           // 256x6400  (pre-smooth p3 input / reg-chain ping; reused post-conv)
#define OFF_T4   1638400u     // 256x1600
#define OFF_T5   2048000u     // 256x400
#define OFF_P3   2150400u     // FPN outputs
#define OFF_P4   3788800u
#define OFF_P5   4198400u
#define OFF_HA3  4300800u     // cls-chain ping
#define OFF_HA4  5939200u
#define OFF_HA5  6348800u
#define OFF_HB3  6451200u     // cls-chain pong (final cls feats)
#define OFF_HB4  8089600u
#define OFF_HB5  8499200u
#define OFF_HD3  8601600u     // reg-chain pong (final reg feats)
#define OFF_HD4  10240000u
#define OFF_HD5  10649600u
#define OFF_CLS  10752000u    // 80x8400 logits
#define OFF_REG  11424000u    // 4x8400
#define OFF_CTN  11457600u    // 8400
// post-processing arrays live in the T3 region (free after the conv stack):
#define POFF_KEYS  (OFF_T3 + 0u)        // 16384 u64  (32768 float slots)
#define POFF_SCS   (OFF_T3 + 32768u)    // 16384 f32  sorted scores
#define POFF_CLSS  (OFF_T3 + 49152u)    // 16384 i32  sorted classes
#define POFF_IDXS  (OFF_T3 + 65536u)    // 16384 i32  sorted anchor idx
#define POFF_GX1   (OFF_T3 + 81920u)    // 8400 each: class-grouped overflow arrays
#define POFF_GY1   (OFF_T3 + 90320u)
#define POFF_GX2   (OFF_T3 + 98720u)
#define POFF_GY2   (OFF_T3 + 107120u)
#define POFF_GAR   (OFF_T3 + 115520u)
#define POFF_GIX   (OFF_T3 + 123920u)
#define POFF_GAL   (OFF_T3 + 132320u)

// ---------------- conv 1x1 (+ optional nearest-up2 add) ----------------
__launch_bounds__(256)
__global__ void conv1x1_kernel(const float* __restrict__ in, const float* __restrict__ w,
                               const float* __restrict__ b, float* __restrict__ out,
                               const float* __restrict__ add,
                               int Cin, int Cout, int NPX, int W, int outStride, int outBase)
{
    __shared__ float s_in[16][64];
    __shared__ float s_w[16][64];
    int t = threadIdx.x;
    int pxg = t & 31, cg = t >> 5;
    int px0 = blockIdx.x * 64;
    int co0 = blockIdx.y * 64;
    float acc[8][2];
#pragma unroll
    for (int c = 0; c < 8; ++c) { acc[c][0] = 0.f; acc[c][1] = 0.f; }
    int chunks = Cin >> 4;
    int wco = t >> 2, wpart = t & 3;
    for (int ch = 0; ch < chunks; ++ch) {
        int ci0 = ch << 4;
#pragma unroll
        for (int k = 0; k < 4; ++k) {
            int id = t + k * 256;
            int ci = id >> 6, pp = id & 63;
            int gp = px0 + pp;
            s_in[ci][pp] = (gp < NPX) ? in[(size_t)(ci0 + ci) * NPX + gp] : 0.f;
        }
        {
            int gco = co0 + wco;
            if (gco < Cout) {
                const float* run = w + (size_t)gco * Cin + ci0;
#pragma unroll
                for (int k = 0; k < 4; ++k) {
                    int e = wpart + 4 * k;
                    s_w[e][wco] = run[e];
                }
            } else {
#pragma unroll
                for (int k = 0; k < 4; ++k) s_w[wpart + 4 * k][wco] = 0.f;
            }
        }
        __syncthreads();
#pragma unroll
        for (int ci = 0; ci < 16; ++ci) {
            float i0 = s_in[ci][pxg * 2], i1 = s_in[ci][pxg * 2 + 1];
#pragma unroll
            for (int c = 0; c < 8; ++c) {
                float wv = s_w[ci][cg * 8 + c];
                acc[c][0] += wv * i0;
                acc[c][1] += wv * i1;
            }
        }
        __syncthreads();
    }
    for (int c = 0; c < 8; ++c) {
        int co = co0 + cg * 8 + c;
        if (co >= Cout) break;
        float bb = b[co];
#pragma unroll
        for (int j = 0; j < 2; ++j) {
            int p = px0 + pxg * 2 + j;
            if (p < NPX) {
                float v = acc[c][j] + bb;
                if (add) {
                    int y = p / W, x = p % W;
                    int Sp = W >> 1;
                    v += add[(size_t)co * (Sp * Sp) + (y >> 1) * Sp + (x >> 1)];
                }
                out[(size_t)co * outStride + outBase + p] = v;
            }
        }
    }
}

// ---------------- conv 3x3, Cin=Cout=256, pad 1 ----------------
template<int TW, int TH, int TCO>
__launch_bounds__(256)
__global__ void conv3x3_t(const float* __restrict__ srcA, const float* __restrict__ srcB,
                          const float* __restrict__ wA, const float* __restrict__ wB,
                          const float* __restrict__ bA, const float* __restrict__ bB,
                          float* __restrict__ dstA, float* __restrict__ dstB,
                          int H, int W, int act)
{
    constexpr int TPX  = TW * TH;
    constexpr int NXQ  = TW / 4;
    constexpr int PXGN = TPX / 4;
    constexpr int COG  = 256 / PXGN;
    constexpr int COPT = TCO / COG;
    constexpr int INW  = TW + 4;
    constexpr int INH  = TH + 2;
    constexpr int INSLOTS = 8 * INH * (TW + 2);
    constexpr int PARTS = 256 / TCO;
    constexpr int EPT   = 72 / PARTS;

    __shared__ float s_in[8][INH][INW];
    __shared__ float s_w[8][9][TCO];

    const float* src = srcA; const float* w = wA; const float* bias = bA; float* dst = dstA;
    if (blockIdx.z == 1) { src = srcB; w = wB; bias = bB; dst = dstB; }

    int t = threadIdx.x;
    int pxg = t % PXGN, cg = t / PXGN;
    int xq = pxg % NXQ, yr = pxg / NXQ;
    int x0 = xq * 4;
    int nTx = (W + TW - 1) / TW;
    int tx = blockIdx.x % nTx, ty = blockIdx.x / nTx;
    int bx0 = tx * TW, by0 = ty * TH;
    int co0 = blockIdx.y * TCO;
    int HW = H * W;

    float acc[COPT][4];
#pragma unroll
    for (int c = 0; c < COPT; ++c)
#pragma unroll
        for (int i = 0; i < 4; ++i) acc[c][i] = 0.f;

    int wco = t / PARTS;
    int wpart = t % PARTS;
    const float* wrunbase = w + (size_t)(co0 + wco) * 256 * 9;

    for (int ch = 0; ch < 32; ++ch) {
        int ci0 = ch * 8;
#pragma unroll
        for (int k = 0; k * 256 < INSLOTS; ++k) {
            int id = t + k * 256;
            if (id < INSLOTS) {
                int ci = id / (INH * (TW + 2));
                int rem = id % (INH * (TW + 2));
                int r = rem / (TW + 2), cc = rem % (TW + 2);
                int gy = by0 - 1 + r, gx = bx0 - 1 + cc;
                float v = 0.f;
                if (gy >= 0 && gy < H && gx >= 0 && gx < W)
                    v = src[(size_t)(ci0 + ci) * HW + gy * W + gx];
                s_in[ci][r][cc] = v;
            }
        }
        {
            const float* run = wrunbase + (size_t)ci0 * 9;
#pragma unroll
            for (int k = 0; k < EPT; ++k) {
                int e = wpart + PARTS * k;
                int ci = e / 9, tap = e % 9;
                s_w[ci][tap][wco] = run[e];
            }
        }
        __syncthreads();
        for (int ci = 0; ci < 8; ++ci) {
            float inr[3][6];
#pragma unroll
            for (int ky = 0; ky < 3; ++ky)
#pragma unroll
                for (int j = 0; j < 6; ++j)
                    inr[ky][j] = s_in[ci][yr + ky][x0 + j];
#pragma unroll
            for (int ky = 0; ky < 3; ++ky) {
#pragma unroll
                for (int kx = 0; kx < 3; ++kx) {
#pragma unroll
                    for (int c = 0; c < COPT; ++c) {
                        float wv = s_w[ci][ky * 3 + kx][cg * COPT + c];
#pragma unroll
                        for (int i = 0; i < 4; ++i)
                            acc[c][i] += wv * inr[ky][kx + i];
                    }
                }
            }
        }
        __syncthreads();
    }
    int y = by0 + yr;
#pragma unroll
    for (int c = 0; c < COPT; ++c) {
        int co = co0 + cg * COPT + c;
        float bb = bias[co];
#pragma unroll
        for (int i = 0; i < 4; ++i) {
            int x = bx0 + x0 + i;
            if (x < W && y < H) {
                float v = acc[c][i] + bb;
                if (act) v = (v >= 0.f) ? v : 0.1f * v;
                dst[(size_t)co * HW + y * W + x] = v;
            }
        }
    }
}

// ---------------- decode: scores, argmax, boxes, sort keys ----------------
__launch_bounds__(256)
__global__ void decode_kernel(const float* __restrict__ cls, const float* __restrict__ reg,
                              const float* __restrict__ ctn, float* __restrict__ out,
                              unsigned long long* __restrict__ keys)
{
    int p = blockIdx.x * 256 + threadIdx.x;
    if (p >= 16384) return;
    if (p >= 8400) { keys[p] = ~0ull; return; }
    int base, hs; float s;
    if (p < 6400)      { base = 0;    hs = 80; s = 8.f;  }
    else if (p < 8000) { base = 6400; hs = 40; s = 16.f; }
    else               { base = 8000; hs = 20; s = 32.f; }
    int local = p - base;
    float gx = (float)(local % hs), gy = (float)(local / hs);
    float ct = ctn[p];
    float sct = 1.f / (1.f + expf(-ct));
    float best = -1.f; int arg = 0;
    for (int c = 0; c < 80; ++c) {
        float v = cls[(size_t)c * 8400 + p];
        float sv = 1.f / (1.f + expf(-v));
        float sc = sqrtf(sv * sct);
        if (sc > best) { best = sc; arg = c; }
    }
    float r0 = reg[0 * 8400 + p], r1 = reg[1 * 8400 + p];
    float r2 = reg[2 * 8400 + p], r3 = reg[3 * 8400 + p];
    float x1 = (gx - expf(r0)) * s / 640.f;
    float y1 = (gy - expf(r1)) * s / 640.f;
    float x2 = (gx + expf(r2)) * s / 640.f;
    float y2 = (gy + expf(r3)) * s / 640.f;
    x1 = fminf(fmaxf(x1, 0.f), 1.f);
    y1 = fminf(fmaxf(y1, 0.f), 1.f);
    x2 = fminf(fmaxf(x2, 0.f), 1.f);
    y2 = fminf(fmaxf(y2, 0.f), 1.f);
    out[p * 4 + 0] = x1; out[p * 4 + 1] = y1;
    out[p * 4 + 2] = x2; out[p * 4 + 3] = y2;
    out[33600 + p] = best;
    out[42000 + p] = (float)arg;
    out[50400 + p] = 0.f;     // keep init
    unsigned int ub = __float_as_uint(best);
    keys[p] = ((unsigned long long)(~ub) << 32) | (unsigned int)p;
}

// ---------------- hybrid bitonic sort of 16384 u64 keys ----------------
// local kernel: 8 blocks x 2048 keys in LDS.
// kmerge==0: full bitonic for k=2..2048.  kmerge==k: merge stages j=1024..1.
__launch_bounds__(256)
__global__ void bitonic_local(unsigned long long* __restrict__ keys, unsigned kmerge)
{
    __shared__ unsigned long long sk[2048];
    int t = threadIdx.x;
    unsigned base = blockIdx.x * 2048u;
#pragma unroll
    for (int m = 0; m < 8; ++m) sk[t + m * 256] = keys[base + t + m * 256];
    __syncthreads();
    if (kmerge == 0u) {
        for (unsigned k = 2; k <= 2048u; k <<= 1) {
            for (unsigned j = k >> 1; j > 0; j >>= 1) {
#pragma unroll
                for (int pp = 0; pp < 4; ++pp) {
                    unsigned p = (unsigned)t + pp * 256u;
                    unsigned li = ((p & ~(j - 1)) << 1) | (p & (j - 1));
                    unsigned gi = base + li;
                    bool up = ((gi & k) == 0);
                    unsigned long long a = sk[li], b = sk[li + j];
                    if ((a > b) == up) { sk[li] = b; sk[li + j] = a; }
                }
                __syncthreads();
            }
        }
    } else {
        unsigned k = kmerge;
        for (unsigned j = 1024; j > 0; j >>= 1) {
#pragma unroll
            for (int pp = 0; pp < 4; ++pp) {
                unsigned p = (unsigned)t + pp * 256u;
                unsigned li = ((p & ~(j - 1)) << 1) | (p & (j - 1));
                unsigned gi = base + li;
                bool up = ((gi & k) == 0);
                unsigned long long a = sk[li], b = sk[li + j];
                if ((a > b) == up) { sk[li] = b; sk[li + j] = a; }
            }
            __syncthreads();
        }
    }
#pragma unroll
    for (int m = 0; m < 8; ++m) keys[base + t + m * 256] = sk[t + m * 256];
}

// global compare-exchange for one (k, j) with j >= 2048. 8192 threads.
__launch_bounds__(256)
__global__ void bitonic_global(unsigned long long* __restrict__ keys, unsigned k, unsigned j)
{
    unsigned p = blockIdx.x * 256u + threadIdx.x;
    unsigned i = ((p & ~(j - 1)) << 1) | (p & (j - 1));
    bool up = ((i & k) == 0);
    unsigned long long a = keys[i], b = keys[i + j];
    if ((a > b) == up) { keys[i] = b; keys[i + j] = a; }
}

// ---------------- expand sorted keys into SoA arrays ----------------
__launch_bounds__(256)
__global__ void sorted_aux(const unsigned long long* __restrict__ keys,
                           const float* __restrict__ out,
                           float* __restrict__ scs, int* __restrict__ clss,
                           int* __restrict__ idxs)
{
    int i = blockIdx.x * 256 + threadIdx.x;
    if (i >= 16384) return;
    unsigned long long key = keys[i];
    unsigned ub = ~(unsigned)(key >> 32);
    float sc = __uint_as_float(ub);
    unsigned idx = (unsigned)(key & 0xffffffffu);
    int cl = -1;
    if (idx < 8400u) cl = (int)out[42000 + idx];
    else sc = 0.f;
    scs[i] = sc; clss[i] = cl; idxs[i] = (int)idx;
}

// ---------------- per-class compact + greedy NMS (1 block per class) ----------------
#define NMSCAP 2048
__launch_bounds__(256)
__global__ void class_nms(const float* __restrict__ scs, const int* __restrict__ clss,
                          const int* __restrict__ idxs, const float* __restrict__ outbuf,
                          float* __restrict__ keep,
                          float* __restrict__ GX1, float* __restrict__ GY1,
                          float* __restrict__ GX2, float* __restrict__ GY2,
                          float* __restrict__ GAR, int* __restrict__ GIX,
                          int* __restrict__ GAL)
{
    int c = blockIdx.x, t = threadIdx.x;
    __shared__ float sx1[NMSCAP], sy1[NMSCAP], sx2[NMSCAP], sy2[NMSCAP], sar[NMSCAP];
    __shared__ int six[NMSCAP];
    __shared__ unsigned char salive[NMSCAP];
    __shared__ int s_red[2];
    __shared__ int s_wtot[4];

    // pass 1: count entries of classes < c (base) and of class c (n)
    int cb = 0, co = 0;
    for (int i = t; i < 16384; i += 256) {
        float sc = scs[i]; int cl = clss[i];
        if (sc >= CONF_T && cl >= 0) { cb += (cl < c); co += (cl == c); }
    }
    if (t == 0) { s_red[0] = 0; s_red[1] = 0; }
    __syncthreads();
    atomicAdd(&s_red[0], cb);
    atomicAdd(&s_red[1], co);
    __syncthreads();
    int base = s_red[0], n = s_red[1];

    // pass 2: stream-compact this class's boxes in sorted order
    int rank = 0;
    for (int st = 0; st < 16384; st += 256) {
        int i = st + t;
        float sc = scs[i]; int cl = clss[i];
        bool flag = (sc >= CONF_T && cl == c);
        unsigned long long m = __ballot(flag);
        int lane = t & 63, wv = t >> 6;
        if (lane == 0) s_wtot[wv] = __popcll(m);
        __syncthreads();
        int off = rank;
        for (int w = 0; w < wv; ++w) off += s_wtot[w];
        int tot = s_wtot[0] + s_wtot[1] + s_wtot[2] + s_wtot[3];
        if (flag) {
            int pos = off + __popcll(m & ((1ull << lane) - 1ull));
            int idx = idxs[i];
            float x1 = outbuf[idx * 4 + 0], y1 = outbuf[idx * 4 + 1];
            float x2 = outbuf[idx * 4 + 2], y2 = outbuf[idx * 4 + 3];
            float ar = (x2 - x1) * (y2 - y1);
            if (pos < NMSCAP) {
                sx1[pos] = x1; sy1[pos] = y1; sx2[pos] = x2; sy2[pos] = y2;
                sar[pos] = ar; six[pos] = idx;
            } else {
                GX1[base + pos] = x1; GY1[base + pos] = y1;
                GX2[base + pos] = x2; GY2[base + pos] = y2;
                GAR[base + pos] = ar; GIX[base + pos] = idx;
            }
        }
        rank += tot;
        __syncthreads();
    }

    // alive init
    for (int s = t; s < n && s < NMSCAP; s += 256) salive[s] = 1;
    for (int s = NMSCAP + t; s < n; s += 256) GAL[base + s] = 1;
    __syncthreads();

    // greedy NMS (order == global sorted order restricted to class c == reference)
    for (int i = 0; i < n; ++i) {
        int a = (i < NMSCAP) ? (int)salive[i] : GAL[base + i];
        if (a) {
            float bx1, by1, bx2, by2, bar_;
            if (i < NMSCAP) { bx1 = sx1[i]; by1 = sy1[i]; bx2 = sx2[i]; by2 = sy2[i]; bar_ = sar[i]; }
            else { bx1 = GX1[base + i]; by1 = GY1[base + i]; bx2 = GX2[base + i]; by2 = GY2[base + i]; bar_ = GAR[base + i]; }
            for (int jb = i + 1 + t; jb < n; jb += 256) {
                int aj = (jb < NMSCAP) ? (int)salive[jb] : GAL[base + jb];
                if (!aj) continue;
                float x1, y1, x2, y2, arj;
                if (jb < NMSCAP) { x1 = sx1[jb]; y1 = sy1[jb]; x2 = sx2[jb]; y2 = sy2[jb]; arj = sar[jb]; }
                else { x1 = GX1[base + jb]; y1 = GY1[base + jb]; x2 = GX2[base + jb]; y2 = GY2[base + jb]; arj = GAR[base + jb]; }
                float xx1 = fmaxf(bx1, x1), yy1 = fmaxf(by1, y1);
                float xx2 = fminf(bx2, x2), yy2 = fminf(by2, y2);
                float ww = fmaxf(1e-28f, xx2 - xx1), hh = fmaxf(1e-28f, yy2 - yy1);
                float inter = ww * hh;
                float ovr = inter / (bar_ + arj - inter);
                if (ovr > NMS_T) {
                    if (jb < NMSCAP) salive[jb] = 0; else GAL[base + jb] = 0;
                }
            }
        }
        __syncthreads();
    }

    // write keep
    for (int s = t; s < n; s += 256) {
        int a = (s < NMSCAP) ? (int)salive[s] : GAL[base + s];
        if (a) {
            int idx = (s < NMSCAP) ? six[s] : GIX[base + s];
            keep[idx] = 1.0f;
        }
    }
}

// ---------------- host orchestration ----------------
extern "C" void kernel_launch(void* const* d_in, const int* in_sizes, int n_in,
                              void* d_out, int out_size, void* d_ws, size_t ws_size,
                              hipStream_t stream)
{
    const float* c3      = (const float*)d_in[0];
    const float* c4      = (const float*)d_in[1];
    const float* c5      = (const float*)d_in[2];
    const float* lat1_w  = (const float*)d_in[3];
    const float* lat1_b  = (const float*)d_in[4];
    const float* lat2_w  = (const float*)d_in[5];
    const float* lat2_b  = (const float*)d_in[6];
    const float* lat3_w  = (const float*)d_in[7];
    const float* lat3_b  = (const float*)d_in[8];
    const float* sm1_w   = (const float*)d_in[9];
    const float* sm1_b   = (const float*)d_in[10];
    const float* sm2_w   = (const float*)d_in[11];
    const float* sm2_b   = (const float*)d_in[12];
    const float* sm3_w   = (const float*)d_in[13];
    const float* sm3_b   = (const float*)d_in[14];
    const float* clsh_w  = (const float*)d_in[15];
    const float* clsh_b  = (const float*)d_in[16];
    const float* regh_w  = (const float*)d_in[17];
    const float* regh_b  = (const float*)d_in[18];
    const float* clsd_w  = (const float*)d_in[19];
    const float* clsd_b  = (const float*)d_in[20];
    const float* regd_w  = (const float*)d_in[21];
    const float* regd_b  = (const float*)d_in[22];
    const float* ctnd_w  = (const float*)d_in[23];
    const float* ctnd_b  = (const float*)d_in[24];

    float* ws = (float*)d_ws;
    float* T3 = ws + OFF_T3;  float* T4 = ws + OFF_T4;  float* T5 = ws + OFF_T5;
    float* P3 = ws + OFF_P3;  float* P4 = ws + OFF_P4;  float* P5 = ws + OFF_P5;
    float* HA3 = ws + OFF_HA3; float* HA4 = ws + OFF_HA4; float* HA5 = ws + OFF_HA5;
    float* HB3 = ws + OFF_HB3; float* HB4 = ws + OFF_HB4; float* HB5 = ws + OFF_HB5;
    float* HD3 = ws + OFF_HD3; float* HD4 = ws + OFF_HD4; float* HD5 = ws + OFF_HD5;
    float* CLS = ws + OFF_CLS; float* REG = ws + OFF_REG; float* CTN = ws + OFF_CTN;
    unsigned long long* KEYS = (unsigned long long*)(ws + POFF_KEYS);
    float* SCS = ws + POFF_SCS;
    int* CLSS = (int*)(ws + POFF_CLSS);
    int* IDXS = (int*)(ws + POFF_IDXS);
    float* GX1 = ws + POFF_GX1; float* GY1 = ws + POFF_GY1;
    float* GX2 = ws + POFF_GX2; float* GY2 = ws + POFF_GY2;
    float* GAR = ws + POFF_GAR;
    int* GIX = (int*)(ws + POFF_GIX);
    int* GAL = (int*)(ws + POFF_GAL);

    float* out = (float*)d_out;
    dim3 blk(256);
    const size_t WSTEP = 256u * 256u * 9u;

    // ---- FPN ----
    conv1x1_kernel<<<dim3(7, 4), blk, 0, stream>>>(c5, lat3_w, lat3_b, T5, nullptr,
                                                   512, 256, 400, 20, 400, 0);
    conv3x3_t<8, 4, 32><<<dim3(15, 8, 1), blk, 0, stream>>>(T5, T5, sm3_w, sm3_w, sm3_b, sm3_b,
                                                            P5, P5, 20, 20, 0);
    conv1x1_kernel<<<dim3(25, 4), blk, 0, stream>>>(c4, lat2_w, lat2_b, T4, T5,
                                                    256, 256, 1600, 40, 1600, 0);
    conv3x3_t<16, 4, 32><<<dim3(30, 8, 1), blk, 0, stream>>>(T4, T4, sm2_w, sm2_w, sm2_b, sm2_b,
                                                             P4, P4, 40, 40, 0);
    conv1x1_kernel<<<dim3(100, 4), blk, 0, stream>>>(c3, lat1_w, lat1_b, T3, T4,
                                                     128, 256, 6400, 80, 6400, 0);
    conv3x3_t<16, 8, 64><<<dim3(50, 4, 1), blk, 0, stream>>>(T3, T3, sm1_w, sm1_w, sm1_b, sm1_b,
                                                             P3, P3, 80, 80, 0);

    // ---- heads ----
    // L3 (80x80)
    {
        float* ping[2][5] = { {P3, HA3, HB3, HA3, HB3},
                              {P3, T3,  HD3, T3,  HD3} };
        for (int i = 0; i < 4; ++i) {
            conv3x3_t<16, 8, 64><<<dim3(50, 4, 2), blk, 0, stream>>>(
                ping[0][i], ping[1][i],
                clsh_w + (size_t)i * WSTEP, regh_w + (size_t)i * WSTEP,
                clsh_b + i * 256, regh_b + i * 256,
                ping[0][i + 1], ping[1][i + 1], 80, 80, 1);
        }
        conv1x1_kernel<<<dim3(100, 2), blk, 0, stream>>>(HB3, clsd_w, clsd_b, CLS, nullptr,
                                                         256, 80, 6400, 80, 8400, 0);
        conv1x1_kernel<<<dim3(100, 1), blk, 0, stream>>>(HD3, regd_w, regd_b, REG, nullptr,
                                                         256, 4, 6400, 80, 8400, 0);
        conv1x1_kernel<<<dim3(100, 1), blk, 0, stream>>>(HD3, ctnd_w, ctnd_b, CTN, nullptr,
                                                         256, 1, 6400, 80, 8400, 0);
    }
    // L4 (40x40)
    {
        float* ping[2][5] = { {P4, HA4, HB4, HA4, HB4},
                              {P4, T4,  HD4, T4,  HD4} };
        for (int i = 0; i < 4; ++i) {
            conv3x3_t<16, 4, 32><<<dim3(30, 8, 2), blk, 0, stream>>>(
                ping[0][i], ping[1][i],
                clsh_w + (size_t)i * WSTEP, regh_w + (size_t)i * WSTEP,
                clsh_b + i * 256, regh_b + i * 256,
                ping[0][i + 1], ping[1][i + 1], 40, 40, 1);
        }
        conv1x1_kernel<<<dim3(25, 2), blk, 0, stream>>>(HB4, clsd_w, clsd_b, CLS, nullptr,
                                                        256, 80, 1600, 40, 8400, 6400);
        conv1x1_kernel<<<dim3(25, 1), blk, 0, stream>>>(HD4, regd_w, regd_b, REG, nullptr,
                                                        256, 4, 1600, 40, 8400, 6400);
        conv1x1_kernel<<<dim3(25, 1), blk, 0, stream>>>(HD4, ctnd_w, ctnd_b, CTN, nullptr,
                                                        256, 1, 1600, 40, 8400, 6400);
    }
    // L5 (20x20)
    {
        float* ping[2][5] = { {P5, HA5, HB5, HA5, HB5},
                              {P5, T5,  HD5, T5,  HD5} };
        for (int i = 0; i < 4; ++i) {
            conv3x3_t<8, 4, 32><<<dim3(15, 8, 2), blk, 0, stream>>>(
                ping[0][i], ping[1][i],
                clsh_w + (size_t)i * WSTEP, regh_w + (size_t)i * WSTEP,
                clsh_b + i * 256, regh_b + i * 256,
                ping[0][i + 1], ping[1][i + 1], 20, 20, 1);
        }
        conv1x1_kernel<<<dim3(7, 2), blk, 0, stream>>>(HB5, clsd_w, clsd_b, CLS, nullptr,
                                                       256, 80, 400, 20, 8400, 8000);
        conv1x1_kernel<<<dim3(7, 1), blk, 0, stream>>>(HD5, regd_w, regd_b, REG, nullptr,
                                                       256, 4, 400, 20, 8400, 8000);
        conv1x1_kernel<<<dim3(7, 1), blk, 0, stream>>>(HD5, ctnd_w, ctnd_b, CTN, nullptr,
                                                       256, 1, 400, 20, 8400, 8000);
    }

    // ---- decode ----
    decode_kernel<<<dim3(64), blk, 0, stream>>>(CLS, REG, CTN, out, KEYS);

    // ---- hybrid bitonic sort (ascending keys = descending score, stable) ----
    bitonic_local<<<dim3(8), blk, 0, stream>>>(KEYS, 0u);
    // k = 4096
    bitonic_global<<<dim3(32), blk, 0, stream>>>(KEYS, 4096u, 2048u);
    bitonic_local<<<dim3(8), blk, 0, stream>>>(KEYS, 4096u);
    // k = 8192
    bitonic_global<<<dim3(32), blk, 0, stream>>>(KEYS, 8192u, 4096u);
    bitonic_global<<<dim3(32), blk, 0, stream>>>(KEYS, 8192u, 2048u);
    bitonic_local<<<dim3(8), blk, 0, stream>>>(KEYS, 8192u);
    // k = 16384
    bitonic_global<<<dim3(32), blk, 0, stream>>>(KEYS, 16384u, 8192u);
    bitonic_global<<<dim3(32), blk, 0, stream>>>(KEYS, 16384u, 4096u);
    bitonic_global<<<dim3(32), blk, 0, stream>>>(KEYS, 16384u, 2048u);
    bitonic_local<<<dim3(8), blk, 0, stream>>>(KEYS, 16384u);

    // ---- expand + per-class NMS ----
    sorted_aux<<<dim3(64), blk, 0, stream>>>(KEYS, out, SCS, CLSS, IDXS);
    class_nms<<<dim3(80), blk, 0, stream>>>(SCS, CLSS, IDXS, out, out + 50400,
                                            GX1, GY1, GX2, GY2, GAR, GIX, GAL);
}

// Round 3
// 4000.651 us; speedup vs baseline: 1.5780x; 1.0507x over previous
//
#include <hip/hip_runtime.h>
#include <stdint.h>

#define CONF_T 0.05f
#define NMS_T  0.5f
#define WMAX   132           // ceil(8400/64)

// ---- workspace layout (float offsets) ----
#define OFF_T3   0u           // 256x6400  (pre-smooth p3 input / reg-chain ping; reused post-conv)
#define OFF_T4   1638400u     // 256x1600
#define OFF_T5   2048000u     // 256x400
#define OFF_P3   2150400u     // FPN outputs
#define OFF_P4   3788800u
#define OFF_P5   4198400u
#define OFF_HA3  4300800u     // cls-chain ping  (post-decode: NMS mask region)
#define OFF_HA4  5939200u
#define OFF_HA5  6348800u
#define OFF_HB3  6451200u     // cls-chain pong (final cls feats)
#define OFF_HB4  8089600u
#define OFF_HB5  8499200u
#define OFF_HD3  8601600u     // reg-chain pong (final reg feats)
#define OFF_HD4  10240000u
#define OFF_HD5  10649600u
#define OFF_CLS  10752000u    // 80x8400 logits
#define OFF_REG  11424000u    // 4x8400
#define OFF_CTN  11457600u    // 8400
// post-processing arrays live in the T3 region (free after the conv stack):
#define POFF_KEYS  (OFF_T3 + 0u)        // 16384 u64  (32768 float slots)
#define POFF_SCS   (OFF_T3 + 32768u)    // 16384 f32  sorted scores
#define POFF_CLSS  (OFF_T3 + 49152u)    // 16384 i32  sorted classes
#define POFF_IDXS  (OFF_T3 + 65536u)    // 16384 i32  sorted anchor idx
#define POFF_GX1   (OFF_T3 + 81920u)    // 8400 each: class-grouped arrays
#define POFF_GY1   (OFF_T3 + 90320u)
#define POFF_GX2   (OFF_T3 + 98720u)
#define POFF_GY2   (OFF_T3 + 107120u)
#define POFF_GAR   (OFF_T3 + 115520u)
#define POFF_GIX   (OFF_T3 + 123920u)
#define POFF_NCNT  (OFF_T3 + 132320u)   // 80 i32 per-class counts
#define POFF_NBASE (OFF_T3 + 132400u)   // 80 i32 per-class bases
// mask region: 8400 rows x 132 u64 words = 8.87 MB, lives in HA3..HB3 (free after detectors)
#define POFF_MASK  OFF_HA3

// ---------------- conv 1x1 (+ optional nearest-up2 add) ----------------
__launch_bounds__(256)
__global__ void conv1x1_kernel(const float* __restrict__ in, const float* __restrict__ w,
                               const float* __restrict__ b, float* __restrict__ out,
                               const float* __restrict__ add,
                               int Cin, int Cout, int NPX, int W, int outStride, int outBase)
{
    __shared__ float s_in[16][64];
    __shared__ float s_w[16][64];
    int t = threadIdx.x;
    int pxg = t & 31, cg = t >> 5;
    int px0 = blockIdx.x * 64;
    int co0 = blockIdx.y * 64;
    float acc[8][2];
#pragma unroll
    for (int c = 0; c < 8; ++c) { acc[c][0] = 0.f; acc[c][1] = 0.f; }
    int chunks = Cin >> 4;
    int wco = t >> 2, wpart = t & 3;
    for (int ch = 0; ch < chunks; ++ch) {
        int ci0 = ch << 4;
#pragma unroll
        for (int k = 0; k < 4; ++k) {
            int id = t + k * 256;
            int ci = id >> 6, pp = id & 63;
            int gp = px0 + pp;
            s_in[ci][pp] = (gp < NPX) ? in[(size_t)(ci0 + ci) * NPX + gp] : 0.f;
        }
        {
            int gco = co0 + wco;
            if (gco < Cout) {
                const float* run = w + (size_t)gco * Cin + ci0;
#pragma unroll
                for (int k = 0; k < 4; ++k) {
                    int e = wpart + 4 * k;
                    s_w[e][wco] = run[e];
                }
            } else {
#pragma unroll
                for (int k = 0; k < 4; ++k) s_w[wpart + 4 * k][wco] = 0.f;
            }
        }
        __syncthreads();
#pragma unroll
        for (int ci = 0; ci < 16; ++ci) {
            float i0 = s_in[ci][pxg * 2], i1 = s_in[ci][pxg * 2 + 1];
#pragma unroll
            for (int c = 0; c < 8; ++c) {
                float wv = s_w[ci][cg * 8 + c];
                acc[c][0] += wv * i0;
                acc[c][1] += wv * i1;
            }
        }
        __syncthreads();
    }
    for (int c = 0; c < 8; ++c) {
        int co = co0 + cg * 8 + c;
        if (co >= Cout) break;
        float bb = b[co];
#pragma unroll
        for (int j = 0; j < 2; ++j) {
            int p = px0 + pxg * 2 + j;
            if (p < NPX) {
                float v = acc[c][j] + bb;
                if (add) {
                    int y = p / W, x = p % W;
                    int Sp = W >> 1;
                    v += add[(size_t)co * (Sp * Sp) + (y >> 1) * Sp + (x >> 1)];
                }
                out[(size_t)co * outStride + outBase + p] = v;
            }
        }
    }
}

// ---------------- conv 3x3, Cin=Cout=256, pad 1 ----------------
template<int TW, int TH, int TCO>
__launch_bounds__(256)
__global__ void conv3x3_t(const float* __restrict__ srcA, const float* __restrict__ srcB,
                          const float* __restrict__ wA, const float* __restrict__ wB,
                          const float* __restrict__ bA, const float* __restrict__ bB,
                          float* __restrict__ dstA, float* __restrict__ dstB,
                          int H, int W, int act)
{
    constexpr int TPX  = TW * TH;
    constexpr int NXQ  = TW / 4;
    constexpr int PXGN = TPX / 4;
    constexpr int COG  = 256 / PXGN;
    constexpr int COPT = TCO / COG;
    constexpr int INW  = TW + 4;
    constexpr int INH  = TH + 2;
    constexpr int INSLOTS = 8 * INH * (TW + 2);
    constexpr int PARTS = 256 / TCO;
    constexpr int EPT   = 72 / PARTS;

    __shared__ float s_in[8][INH][INW];
    __shared__ float s_w[8][9][TCO];

    const float* src = srcA; const float* w = wA; const float* bias = bA; float* dst = dstA;
    if (blockIdx.z == 1) { src = srcB; w = wB; bias = bB; dst = dstB; }

    int t = threadIdx.x;
    int pxg = t % PXGN, cg = t / PXGN;
    int xq = pxg % NXQ, yr = pxg / NXQ;
    int x0 = xq * 4;
    int nTx = (W + TW - 1) / TW;
    int tx = blockIdx.x % nTx, ty = blockIdx.x / nTx;
    int bx0 = tx * TW, by0 = ty * TH;
    int co0 = blockIdx.y * TCO;
    int HW = H * W;

    float acc[COPT][4];
#pragma unroll
    for (int c = 0; c < COPT; ++c)
#pragma unroll
        for (int i = 0; i < 4; ++i) acc[c][i] = 0.f;

    int wco = t / PARTS;
    int wpart = t % PARTS;
    const float* wrunbase = w + (size_t)(co0 + wco) * 256 * 9;

    for (int ch = 0; ch < 32; ++ch) {
        int ci0 = ch * 8;
#pragma unroll
        for (int k = 0; k * 256 < INSLOTS; ++k) {
            int id = t + k * 256;
            if (id < INSLOTS) {
                int ci = id / (INH * (TW + 2));
                int rem = id % (INH * (TW + 2));
                int r = rem / (TW + 2), cc = rem % (TW + 2);
                int gy = by0 - 1 + r, gx = bx0 - 1 + cc;
                float v = 0.f;
                if (gy >= 0 && gy < H && gx >= 0 && gx < W)
                    v = src[(size_t)(ci0 + ci) * HW + gy * W + gx];
                s_in[ci][r][cc] = v;
            }
        }
        {
            const float* run = wrunbase + (size_t)ci0 * 9;
#pragma unroll
            for (int k = 0; k < EPT; ++k) {
                int e = wpart + PARTS * k;
                int ci = e / 9, tap = e % 9;
                s_w[ci][tap][wco] = run[e];
            }
        }
        __syncthreads();
        for (int ci = 0; ci < 8; ++ci) {
            float inr[3][6];
#pragma unroll
            for (int ky = 0; ky < 3; ++ky)
#pragma unroll
                for (int j = 0; j < 6; ++j)
                    inr[ky][j] = s_in[ci][yr + ky][x0 + j];
#pragma unroll
            for (int ky = 0; ky < 3; ++ky) {
#pragma unroll
                for (int kx = 0; kx < 3; ++kx) {
#pragma unroll
                    for (int c = 0; c < COPT; ++c) {
                        float wv = s_w[ci][ky * 3 + kx][cg * COPT + c];
#pragma unroll
                        for (int i = 0; i < 4; ++i)
                            acc[c][i] += wv * inr[ky][kx + i];
                    }
                }
            }
        }
        __syncthreads();
    }
    int y = by0 + yr;
#pragma unroll
    for (int c = 0; c < COPT; ++c) {
        int co = co0 + cg * COPT + c;
        float bb = bias[co];
#pragma unroll
        for (int i = 0; i < 4; ++i) {
            int x = bx0 + x0 + i;
            if (x < W && y < H) {
                float v = acc[c][i] + bb;
                if (act) v = (v >= 0.f) ? v : 0.1f * v;
                dst[(size_t)co * HW + y * W + x] = v;
            }
        }
    }
}

// ---------------- decode: scores, argmax, boxes, sort keys ----------------
__launch_bounds__(256)
__global__ void decode_kernel(const float* __restrict__ cls, const float* __restrict__ reg,
                              const float* __restrict__ ctn, float* __restrict__ out,
                              unsigned long long* __restrict__ keys)
{
    int p = blockIdx.x * 256 + threadIdx.x;
    if (p >= 16384) return;
    if (p >= 8400) { keys[p] = ~0ull; return; }
    int base, hs; float s;
    if (p < 6400)      { base = 0;    hs = 80; s = 8.f;  }
    else if (p < 8000) { base = 6400; hs = 40; s = 16.f; }
    else               { base = 8000; hs = 20; s = 32.f; }
    int local = p - base;
    float gx = (float)(local % hs), gy = (float)(local / hs);
    float ct = ctn[p];
    float sct = 1.f / (1.f + expf(-ct));
    float best = -1.f; int arg = 0;
    for (int c = 0; c < 80; ++c) {
        float v = cls[(size_t)c * 8400 + p];
        float sv = 1.f / (1.f + expf(-v));
        float sc = sqrtf(sv * sct);
        if (sc > best) { best = sc; arg = c; }
    }
    float r0 = reg[0 * 8400 + p], r1 = reg[1 * 8400 + p];
    float r2 = reg[2 * 8400 + p], r3 = reg[3 * 8400 + p];
    float x1 = (gx - expf(r0)) * s / 640.f;
    float y1 = (gy - expf(r1)) * s / 640.f;
    float x2 = (gx + expf(r2)) * s / 640.f;
    float y2 = (gy + expf(r3)) * s / 640.f;
    x1 = fminf(fmaxf(x1, 0.f), 1.f);
    y1 = fminf(fmaxf(y1, 0.f), 1.f);
    x2 = fminf(fmaxf(x2, 0.f), 1.f);
    y2 = fminf(fmaxf(y2, 0.f), 1.f);
    out[p * 4 + 0] = x1; out[p * 4 + 1] = y1;
    out[p * 4 + 2] = x2; out[p * 4 + 3] = y2;
    out[33600 + p] = best;
    out[42000 + p] = (float)arg;
    out[50400 + p] = 0.f;     // keep init
    unsigned int ub = __float_as_uint(best);
    keys[p] = ((unsigned long long)(~ub) << 32) | (unsigned int)p;
}

// ---------------- hybrid bitonic sort of 16384 u64 keys ----------------
__launch_bounds__(256)
__global__ void bitonic_local(unsigned long long* __restrict__ keys, unsigned kmerge)
{
    __shared__ unsigned long long sk[2048];
    int t = threadIdx.x;
    unsigned base = blockIdx.x * 2048u;
#pragma unroll
    for (int m = 0; m < 8; ++m) sk[t + m * 256] = keys[base + t + m * 256];
    __syncthreads();
    if (kmerge == 0u) {
        for (unsigned k = 2; k <= 2048u; k <<= 1) {
            for (unsigned j = k >> 1; j > 0; j >>= 1) {
#pragma unroll
                for (int pp = 0; pp < 4; ++pp) {
                    unsigned p = (unsigned)t + pp * 256u;
                    unsigned li = ((p & ~(j - 1)) << 1) | (p & (j - 1));
                    unsigned gi = base + li;
                    bool up = ((gi & k) == 0);
                    unsigned long long a = sk[li], b = sk[li + j];
                    if ((a > b) == up) { sk[li] = b; sk[li + j] = a; }
                }
                __syncthreads();
            }
        }
    } else {
        unsigned k = kmerge;
        for (unsigned j = 1024; j > 0; j >>= 1) {
#pragma unroll
            for (int pp = 0; pp < 4; ++pp) {
                unsigned p = (unsigned)t + pp * 256u;
                unsigned li = ((p & ~(j - 1)) << 1) | (p & (j - 1));
                unsigned gi = base + li;
                bool up = ((gi & k) == 0);
                unsigned long long a = sk[li], b = sk[li + j];
                if ((a > b) == up) { sk[li] = b; sk[li + j] = a; }
            }
            __syncthreads();
        }
    }
#pragma unroll
    for (int m = 0; m < 8; ++m) keys[base + t + m * 256] = sk[t + m * 256];
}

__launch_bounds__(256)
__global__ void bitonic_global(unsigned long long* __restrict__ keys, unsigned k, unsigned j)
{
    unsigned p = blockIdx.x * 256u + threadIdx.x;
    unsigned i = ((p & ~(j - 1)) << 1) | (p & (j - 1));
    bool up = ((i & k) == 0);
    unsigned long long a = keys[i], b = keys[i + j];
    if ((a > b) == up) { keys[i] = b; keys[i + j] = a; }
}

// ---------------- expand sorted keys into SoA arrays ----------------
__launch_bounds__(256)
__global__ void sorted_aux(const unsigned long long* __restrict__ keys,
                           const float* __restrict__ out,
                           float* __restrict__ scs, int* __restrict__ clss,
                           int* __restrict__ idxs)
{
    int i = blockIdx.x * 256 + threadIdx.x;
    if (i >= 16384) return;
    unsigned long long key = keys[i];
    unsigned ub = ~(unsigned)(key >> 32);
    float sc = __uint_as_float(ub);
    unsigned idx = (unsigned)(key & 0xffffffffu);
    int cl = -1;
    if (idx < 8400u) cl = (int)out[42000 + idx];
    else sc = 0.f;
    scs[i] = sc; clss[i] = cl; idxs[i] = (int)idx;
}

// ---------------- NMS stage 1: per-class stable compaction ----------------
__launch_bounds__(256)
__global__ void compact_cls(const float* __restrict__ scs, const int* __restrict__ clss,
                            const int* __restrict__ idxs, const float* __restrict__ outbuf,
                            float* __restrict__ GX1, float* __restrict__ GY1,
                            float* __restrict__ GX2, float* __restrict__ GY2,
                            float* __restrict__ GAR, int* __restrict__ GIX,
                            int* __restrict__ NCOUNT, int* __restrict__ NBASE)
{
    int c = blockIdx.x, t = threadIdx.x;
    __shared__ int s_red[2];
    __shared__ int s_wtot[4];
    int cb = 0, co = 0;
    for (int i = t; i < 16384; i += 256) {
        float sc = scs[i]; int cl = clss[i];
        if (sc >= CONF_T && cl >= 0) { cb += (cl < c); co += (cl == c); }
    }
    if (t == 0) { s_red[0] = 0; s_red[1] = 0; }
    __syncthreads();
    atomicAdd(&s_red[0], cb);
    atomicAdd(&s_red[1], co);
    __syncthreads();
    int base = s_red[0], n = s_red[1];
    if (t == 0) { NCOUNT[c] = n; NBASE[c] = base; }

    int rank = 0;
    for (int st = 0; st < 16384; st += 256) {
        int i = st + t;
        float sc = scs[i]; int cl = clss[i];
        bool flag = (sc >= CONF_T && cl == c);
        unsigned long long m = __ballot(flag);
        int lane = t & 63, wv = t >> 6;
        if (lane == 0) s_wtot[wv] = __popcll(m);
        __syncthreads();
        int off = rank;
        for (int w = 0; w < wv; ++w) off += s_wtot[w];
        int tot = s_wtot[0] + s_wtot[1] + s_wtot[2] + s_wtot[3];
        if (flag) {
            int pos = off + __popcll(m & ((1ull << lane) - 1ull));
            int idx = idxs[i];
            float x1 = outbuf[idx * 4 + 0], y1 = outbuf[idx * 4 + 1];
            float x2 = outbuf[idx * 4 + 2], y2 = outbuf[idx * 4 + 3];
            GX1[base + pos] = x1; GY1[base + pos] = y1;
            GX2[base + pos] = x2; GY2[base + pos] = y2;
            GAR[base + pos] = (x2 - x1) * (y2 - y1);
            GIX[base + pos] = idx;
        }
        rank += tot;
        __syncthreads();
    }
}

// ---------------- NMS stage 2: suppression bit-matrix (parallel) ----------------
// grid (33, 80): block fills rows [bx*256, bx*256+256) of class by's mask.
__launch_bounds__(256)
__global__ void nms_mask(const float* __restrict__ GX1, const float* __restrict__ GY1,
                         const float* __restrict__ GX2, const float* __restrict__ GY2,
                         const float* __restrict__ GAR,
                         const int* __restrict__ NCOUNT, const int* __restrict__ NBASE,
                         unsigned long long* __restrict__ MASK)
{
    int c = blockIdx.y;
    int n = NCOUNT[c];
    if ((int)(blockIdx.x * 256) >= n) return;
    int base = NBASE[c];
    int t = threadIdx.x;
    int r = blockIdx.x * 256 + t;
    bool hav = (r < n);
    float rx1 = 0.f, ry1 = 0.f, rx2 = 0.f, ry2 = 0.f, rar = 0.f;
    if (hav) {
        rx1 = GX1[base + r]; ry1 = GY1[base + r];
        rx2 = GX2[base + r]; ry2 = GY2[base + r];
        rar = GAR[base + r];
    }
    __shared__ float tx1[2048], ty1[2048], tx2[2048], ty2[2048], tar[2048];
    for (int jt = 0; jt < n; jt += 2048) {
        int cnt = min(2048, n - jt);
        __syncthreads();
        for (int k = t; k < cnt; k += 256) {
            tx1[k] = GX1[base + jt + k]; ty1[k] = GY1[base + jt + k];
            tx2[k] = GX2[base + jt + k]; ty2[k] = GY2[base + jt + k];
            tar[k] = GAR[base + jt + k];
        }
        __syncthreads();
        if (hav) {
            int w0 = jt >> 6;
            int nw = (cnt + 63) >> 6;
            for (int w = 0; w < nw; ++w) {
                int jb = jt + w * 64;
                unsigned long long bits = 0ull;
                if (jb + 63 > r) {
                    int kmax = min(64, n - jb);
                    for (int kk = 0; kk < kmax; ++kk) {
                        int j = jb + kk;
                        if (j > r) {
                            int k2 = j - jt;
                            float xx1 = fmaxf(rx1, tx1[k2]);
                            float yy1 = fmaxf(ry1, ty1[k2]);
                            float xx2 = fminf(rx2, tx2[k2]);
                            float yy2 = fminf(ry2, ty2[k2]);
                            float ww = fmaxf(1e-28f, xx2 - xx1);
                            float hh = fmaxf(1e-28f, yy2 - yy1);
                            float inter = ww * hh;
                            float ovr = inter / (rar + tar[k2] - inter);
                            if (ovr > NMS_T) bits |= (1ull << kk);
                        }
                    }
                }
                MASK[(size_t)(base + r) * WMAX + w0 + w] = bits;
            }
        }
    }
}

// ---------------- NMS stage 3: chunked bitmask scan (80 blocks) ----------------
__launch_bounds__(256)
__global__ void nms_scan(const unsigned long long* __restrict__ MASK,
                         const int* __restrict__ GIX,
                         const int* __restrict__ NCOUNT, const int* __restrict__ NBASE,
                         float* __restrict__ keep)
{
    int c = blockIdx.x, t = threadIdx.x;
    int n = NCOUNT[c];
    if (n == 0) return;
    int base = NBASE[c];
    int Wc = (n + 63) >> 6;
    __shared__ unsigned long long remv[WMAX];
    __shared__ unsigned long long sld[32][WMAX];
    __shared__ unsigned int s_alive;
    for (int w = t; w < Wc; w += 256) remv[w] = 0ull;
    __syncthreads();
    for (int i0 = 0; i0 < n; i0 += 32) {
        int rows = min(32, n - i0);
        int tot = rows * Wc;
        for (int k = t; k < tot; k += 256) {
            int rr = k / Wc, w = k - rr * Wc;
            sld[rr][w] = MASK[(size_t)(base + i0 + rr) * WMAX + w];
        }
        __syncthreads();
        if (t == 0) {
            int wq = i0 >> 6, b0 = i0 & 63;
            unsigned long long lw = remv[wq];
            unsigned am = 0;
            for (int rr = 0; rr < rows; ++rr) {
                if (!((lw >> (b0 + rr)) & 1ull)) {
                    am |= (1u << rr);
                    lw |= sld[rr][wq];
                }
            }
            s_alive = am;
        }
        __syncthreads();
        unsigned am = s_alive;
        for (int w = t; w < Wc; w += 256) {
            unsigned long long acc = remv[w];
            unsigned m = am;
            while (m) { int rr = __ffs(m) - 1; m &= m - 1; acc |= sld[rr][w]; }
            remv[w] = acc;
        }
        if (t < rows && ((am >> t) & 1u)) keep[GIX[base + i0 + t]] = 1.0f;
        __syncthreads();
    }
}

// ---------------- host orchestration ----------------
extern "C" void kernel_launch(void* const* d_in, const int* in_sizes, int n_in,
                              void* d_out, int out_size, void* d_ws, size_t ws_size,
                              hipStream_t stream)
{
    const float* c3      = (const float*)d_in[0];
    const float* c4      = (const float*)d_in[1];
    const float* c5      = (const float*)d_in[2];
    const float* lat1_w  = (const float*)d_in[3];
    const float* lat1_b  = (const float*)d_in[4];
    const float* lat2_w  = (const float*)d_in[5];
    const float* lat2_b  = (const float*)d_in[6];
    const float* lat3_w  = (const float*)d_in[7];
    const float* lat3_b  = (const float*)d_in[8];
    const float* sm1_w   = (const float*)d_in[9];
    const float* sm1_b   = (const float*)d_in[10];
    const float* sm2_w   = (const float*)d_in[11];
    const float* sm2_b   = (const float*)d_in[12];
    const float* sm3_w   = (const float*)d_in[13];
    const float* sm3_b   = (const float*)d_in[14];
    const float* clsh_w  = (const float*)d_in[15];
    const float* clsh_b  = (const float*)d_in[16];
    const float* regh_w  = (const float*)d_in[17];
    const float* regh_b  = (const float*)d_in[18];
    const float* clsd_w  = (const float*)d_in[19];
    const float* clsd_b  = (const float*)d_in[20];
    const float* regd_w  = (const float*)d_in[21];
    const float* regd_b  = (const float*)d_in[22];
    const float* ctnd_w  = (const float*)d_in[23];
    const float* ctnd_b  = (const float*)d_in[24];

    float* ws = (float*)d_ws;
    float* T3 = ws + OFF_T3;  float* T4 = ws + OFF_T4;  float* T5 = ws + OFF_T5;
    float* P3 = ws + OFF_P3;  float* P4 = ws + OFF_P4;  float* P5 = ws + OFF_P5;
    float* HA3 = ws + OFF_HA3; float* HA4 = ws + OFF_HA4; float* HA5 = ws + OFF_HA5;
    float* HB3 = ws + OFF_HB3; float* HB4 = ws + OFF_HB4; float* HB5 = ws + OFF_HB5;
    float* HD3 = ws + OFF_HD3; float* HD4 = ws + OFF_HD4; float* HD5 = ws + OFF_HD5;
    float* CLS = ws + OFF_CLS; float* REG = ws + OFF_REG; float* CTN = ws + OFF_CTN;
    unsigned long long* KEYS = (unsigned long long*)(ws + POFF_KEYS);
    float* SCS = ws + POFF_SCS;
    int* CLSS = (int*)(ws + POFF_CLSS);
    int* IDXS = (int*)(ws + POFF_IDXS);
    float* GX1 = ws + POFF_GX1; float* GY1 = ws + POFF_GY1;
    float* GX2 = ws + POFF_GX2; float* GY2 = ws + POFF_GY2;
    float* GAR = ws + POFF_GAR;
    int* GIX = (int*)(ws + POFF_GIX);
    int* NCOUNT = (int*)(ws + POFF_NCNT);
    int* NBASE  = (int*)(ws + POFF_NBASE);
    unsigned long long* MASK = (unsigned long long*)(ws + POFF_MASK);

    float* out = (float*)d_out;
    dim3 blk(256);
    const size_t WSTEP = 256u * 256u * 9u;

    // ---- FPN ----
    conv1x1_kernel<<<dim3(7, 4), blk, 0, stream>>>(c5, lat3_w, lat3_b, T5, nullptr,
                                                   512, 256, 400, 20, 400, 0);
    conv3x3_t<8, 4, 32><<<dim3(15, 8, 1), blk, 0, stream>>>(T5, T5, sm3_w, sm3_w, sm3_b, sm3_b,
                                                            P5, P5, 20, 20, 0);
    conv1x1_kernel<<<dim3(25, 4), blk, 0, stream>>>(c4, lat2_w, lat2_b, T4, T5,
                                                    256, 256, 1600, 40, 1600, 0);
    conv3x3_t<16, 4, 32><<<dim3(30, 8, 1), blk, 0, stream>>>(T4, T4, sm2_w, sm2_w, sm2_b, sm2_b,
                                                             P4, P4, 40, 40, 0);
    conv1x1_kernel<<<dim3(100, 4), blk, 0, stream>>>(c3, lat1_w, lat1_b, T3, T4,
                                                     128, 256, 6400, 80, 6400, 0);
    conv3x3_t<16, 8, 32><<<dim3(50, 8, 1), blk, 0, stream>>>(T3, T3, sm1_w, sm1_w, sm1_b, sm1_b,
                                                             P3, P3, 80, 80, 0);

    // ---- heads ----
    // L3 (80x80)
    {
        float* ping[2][5] = { {P3, HA3, HB3, HA3, HB3},
                              {P3, T3,  HD3, T3,  HD3} };
        for (int i = 0; i < 4; ++i) {
            conv3x3_t<16, 8, 32><<<dim3(50, 8, 2), blk, 0, stream>>>(
                ping[0][i], ping[1][i],
                clsh_w + (size_t)i * WSTEP, regh_w + (size_t)i * WSTEP,
                clsh_b + i * 256, regh_b + i * 256,
                ping[0][i + 1], ping[1][i + 1], 80, 80, 1);
        }
        conv1x1_kernel<<<dim3(100, 2), blk, 0, stream>>>(HB3, clsd_w, clsd_b, CLS, nullptr,
                                                         256, 80, 6400, 80, 8400, 0);
        conv1x1_kernel<<<dim3(100, 1), blk, 0, stream>>>(HD3, regd_w, regd_b, REG, nullptr,
                                                         256, 4, 6400, 80, 8400, 0);
        conv1x1_kernel<<<dim3(100, 1), blk, 0, stream>>>(HD3, ctnd_w, ctnd_b, CTN, nullptr,
                                                         256, 1, 6400, 80, 8400, 0);
    }
    // L4 (40x40)
    {
        float* ping[2][5] = { {P4, HA4, HB4, HA4, HB4},
                              {P4, T4,  HD4, T4,  HD4} };
        for (int i = 0; i < 4; ++i) {
            conv3x3_t<16, 4, 32><<<dim3(30, 8, 2), blk, 0, stream>>>(
                ping[0][i], ping[1][i],
                clsh_w + (size_t)i * WSTEP, regh_w + (size_t)i * WSTEP,
                clsh_b + i * 256, regh_b + i * 256,
                ping[0][i + 1], ping[1][i + 1], 40, 40, 1);
        }
        conv1x1_kernel<<<dim3(25, 2), blk, 0, stream>>>(HB4, clsd_w, clsd_b, CLS, nullptr,
                                                        256, 80, 1600, 40, 8400, 6400);
        conv1x1_kernel<<<dim3(25, 1), blk, 0, stream>>>(HD4, regd_w, regd_b, REG, nullptr,
                                                        256, 4, 1600, 40, 8400, 6400);
        conv1x1_kernel<<<dim3(25, 1), blk, 0, stream>>>(HD4, ctnd_w, ctnd_b, CTN, nullptr,
                                                        256, 1, 1600, 40, 8400, 6400);
    }
    // L5 (20x20)
    {
        float* ping[2][5] = { {P5, HA5, HB5, HA5, HB5},
                              {P5, T5,  HD5, T5,  HD5} };
        for (int i = 0; i < 4; ++i) {
            conv3x3_t<8, 4, 32><<<dim3(15, 8, 2), blk, 0, stream>>>(
                ping[0][i], ping[1][i],
                clsh_w + (size_t)i * WSTEP, regh_w + (size_t)i * WSTEP,
                clsh_b + i * 256, regh_b + i * 256,
                ping[0][i + 1], ping[1][i + 1], 20, 20, 1);
        }
        conv1x1_kernel<<<dim3(7, 2), blk, 0, stream>>>(HB5, clsd_w, clsd_b, CLS, nullptr,
                                                       256, 80, 400, 20, 8400, 8000);
        conv1x1_kernel<<<dim3(7, 1), blk, 0, stream>>>(HD5, regd_w, regd_b, REG, nullptr,
                                                       256, 4, 400, 20, 8400, 8000);
        conv1x1_kernel<<<dim3(7, 1), blk, 0, stream>>>(HD5, ctnd_w, ctnd_b, CTN, nullptr,
                                                       256, 1, 400, 20, 8400, 8000);
    }

    // ---- decode ----
    decode_kernel<<<dim3(64), blk, 0, stream>>>(CLS, REG, CTN, out, KEYS);

    // ---- hybrid bitonic sort ----
    bitonic_local<<<dim3(8), blk, 0, stream>>>(KEYS, 0u);
    bitonic_global<<<dim3(32), blk, 0, stream>>>(KEYS, 4096u, 2048u);
    bitonic_local<<<dim3(8), blk, 0, stream>>>(KEYS, 4096u);
    bitonic_global<<<dim3(32), blk, 0, stream>>>(KEYS, 8192u, 4096u);
    bitonic_global<<<dim3(32), blk, 0, stream>>>(KEYS, 8192u, 2048u);
    bitonic_local<<<dim3(8), blk, 0, stream>>>(KEYS, 8192u);
    bitonic_global<<<dim3(32), blk, 0, stream>>>(KEYS, 16384u, 8192u);
    bitonic_global<<<dim3(32), blk, 0, stream>>>(KEYS, 16384u, 4096u);
    bitonic_global<<<dim3(32), blk, 0, stream>>>(KEYS, 16384u, 2048u);
    bitonic_local<<<dim3(8), blk, 0, stream>>>(KEYS, 16384u);

    // ---- NMS pipeline ----
    sorted_aux<<<dim3(64), blk, 0, stream>>>(KEYS, out, SCS, CLSS, IDXS);
    compact_cls<<<dim3(80), blk, 0, stream>>>(SCS, CLSS, IDXS, out,
                                              GX1, GY1, GX2, GY2, GAR, GIX, NCOUNT, NBASE);
    nms_mask<<<dim3(33, 80), blk, 0, stream>>>(GX1, GY1, GX2, GY2, GAR, NCOUNT, NBASE, MASK);
    nms_scan<<<dim3(80), blk, 0, stream>>>(MASK, GIX, NCOUNT, NBASE, out + 50400);
}

// Round 4
// 3442.365 us; speedup vs baseline: 1.8339x; 1.1622x over previous
//
#include <hip/hip_runtime.h>
#include <stdint.h>

#define CONF_T 0.05f
#define NMS_T  0.5f
#define WMAX   132           // ceil(8400/64)

// ---- workspace layout (float offsets) ----
#define OFF_T3   0u           // 256x6400  (pre-smooth p3 input / reg-chain ping; reused post-conv)
#define OFF_T4   1638400u     // 256x1600
#define OFF_T5   2048000u     // 256x400
#define OFF_P3   2150400u     // FPN outputs
#define OFF_P4   3788800u
#define OFF_P5   4198400u
#define OFF_HA3  4300800u     // cls-chain ping  (post-decode: NMS mask region)
#define OFF_HA4  5939200u
#define OFF_HA5  6348800u
#define OFF_HB3  6451200u     // cls-chain pong (final cls feats)
#define OFF_HB4  8089600u
#define OFF_HB5  8499200u
#define OFF_HD3  8601600u     // reg-chain pong (final reg feats)
#define OFF_HD4  10240000u
#define OFF_HD5  10649600u
#define OFF_CLS  10752000u    // 80x8400 logits
#define OFF_REG  11424000u    // 4x8400
#define OFF_CTN  11457600u    // 8400
// post-processing arrays live in the T3 region (free after the conv stack):
#define POFF_KEYS  (OFF_T3 + 0u)        // 16384 u64  (32768 float slots)
#define POFF_SCS   (OFF_T3 + 32768u)    // 16384 f32  sorted scores
#define POFF_CLSS  (OFF_T3 + 49152u)    // 16384 i32  sorted classes
#define POFF_IDXS  (OFF_T3 + 65536u)    // 16384 i32  sorted anchor idx
#define POFF_GX1   (OFF_T3 + 81920u)    // 8400 each: class-grouped arrays
#define POFF_GY1   (OFF_T3 + 90320u)
#define POFF_GX2   (OFF_T3 + 98720u)
#define POFF_GY2   (OFF_T3 + 107120u)
#define POFF_GAR   (OFF_T3 + 115520u)
#define POFF_GIX   (OFF_T3 + 123920u)
#define POFF_NCNT  (OFF_T3 + 132320u)   // 80 i32 per-class counts
#define POFF_NBASE (OFF_T3 + 132400u)   // 80 i32 per-class bases
// mask region: 8400 rows x 132 u64 words = 8.87 MB, lives in HA3..HB3 (free after detectors)
#define POFF_MASK  OFF_HA3

// ---------------- conv 1x1 (+ optional nearest-up2 add) ----------------
__launch_bounds__(256)
__global__ void conv1x1_kernel(const float* __restrict__ in, const float* __restrict__ w,
                               const float* __restrict__ b, float* __restrict__ out,
                               const float* __restrict__ add,
                               int Cin, int Cout, int NPX, int W, int outStride, int outBase)
{
    __shared__ float s_in[16][64];
    __shared__ float s_w[16][64];
    int t = threadIdx.x;
    int pxg = t & 31, cg = t >> 5;
    int px0 = blockIdx.x * 64;
    int co0 = blockIdx.y * 64;
    float acc[8][2];
#pragma unroll
    for (int c = 0; c < 8; ++c) { acc[c][0] = 0.f; acc[c][1] = 0.f; }
    int chunks = Cin >> 4;
    int wco = t >> 2, wpart = t & 3;
    for (int ch = 0; ch < chunks; ++ch) {
        int ci0 = ch << 4;
#pragma unroll
        for (int k = 0; k < 4; ++k) {
            int id = t + k * 256;
            int ci = id >> 6, pp = id & 63;
            int gp = px0 + pp;
            s_in[ci][pp] = (gp < NPX) ? in[(size_t)(ci0 + ci) * NPX + gp] : 0.f;
        }
        {
            int gco = co0 + wco;
            if (gco < Cout) {
                const float* run = w + (size_t)gco * Cin + ci0;
#pragma unroll
                for (int k = 0; k < 4; ++k) {
                    int e = wpart + 4 * k;
                    s_w[e][wco] = run[e];
                }
            } else {
#pragma unroll
                for (int k = 0; k < 4; ++k) s_w[wpart + 4 * k][wco] = 0.f;
            }
        }
        __syncthreads();
#pragma unroll
        for (int ci = 0; ci < 16; ++ci) {
            float i0 = s_in[ci][pxg * 2], i1 = s_in[ci][pxg * 2 + 1];
#pragma unroll
            for (int c = 0; c < 8; ++c) {
                float wv = s_w[ci][cg * 8 + c];
                acc[c][0] += wv * i0;
                acc[c][1] += wv * i1;
            }
        }
        __syncthreads();
    }
    for (int c = 0; c < 8; ++c) {
        int co = co0 + cg * 8 + c;
        if (co >= Cout) break;
        float bb = b[co];
#pragma unroll
        for (int j = 0; j < 2; ++j) {
            int p = px0 + pxg * 2 + j;
            if (p < NPX) {
                float v = acc[c][j] + bb;
                if (add) {
                    int y = p / W, x = p % W;
                    int Sp = W >> 1;
                    v += add[(size_t)co * (Sp * Sp) + (y >> 1) * Sp + (x >> 1)];
                }
                out[(size_t)co * outStride + outBase + p] = v;
            }
        }
    }
}

// ---------------- conv 3x3, Cin=Cout=256, pad 1 ----------------
// INW = TW+5 (ODD dword row stride): bank = (21*yr + 4*xq) mod 32 -> worst 2-way
// (free on CDNA4) instead of the 4-way conflict at stride 20 (all addrs = 0 mod 4).
// Staging address math (div/mod + border tests) hoisted out of the 32-chunk loop.
template<int TW, int TH, int TCO>
__launch_bounds__(256)
__global__ void conv3x3_t(const float* __restrict__ srcA, const float* __restrict__ srcB,
                          const float* __restrict__ wA, const float* __restrict__ wB,
                          const float* __restrict__ bA, const float* __restrict__ bB,
                          float* __restrict__ dstA, float* __restrict__ dstB,
                          int H, int W, int act)
{
    constexpr int TPX  = TW * TH;
    constexpr int NXQ  = TW / 4;
    constexpr int PXGN = TPX / 4;
    constexpr int COG  = 256 / PXGN;
    constexpr int COPT = TCO / COG;
    constexpr int INW  = TW + 5;       // odd stride -> conflict-free reads
    constexpr int INH  = TH + 2;
    constexpr int SW   = TW + 2;
    constexpr int INSLOTS = 8 * INH * SW;
    constexpr int KSTG = (INSLOTS + 255) / 256;
    constexpr int PARTS = 256 / TCO;
    constexpr int EPT   = 72 / PARTS;

    __shared__ float s_in[8][INH][INW];
    __shared__ float s_w[8 * 9 * TCO];

    const float* src = srcA; const float* w = wA; const float* bias = bA; float* dst = dstA;
    if (blockIdx.z == 1) { src = srcB; w = wB; bias = bB; dst = dstB; }

    int t = threadIdx.x;
    int pxg = t % PXGN, cg = t / PXGN;
    int xq = pxg % NXQ, yr = pxg / NXQ;
    int x0 = xq * 4;
    int nTx = (W + TW - 1) / TW;
    int tx = blockIdx.x % nTx, ty = blockIdx.x / nTx;
    int bx0 = tx * TW, by0 = ty * TH;
    int co0 = blockIdx.y * TCO;
    int HW = H * W;

    // ---- ch-invariant staging descriptors ----
    int sl[KSTG];   // LDS flat offset (or -1)
    int sg[KSTG];   // global offset within 8-channel slab (or -1 -> zero pad)
#pragma unroll
    for (int k = 0; k < KSTG; ++k) {
        int id = t + k * 256;
        sl[k] = -1; sg[k] = -1;
        if (id < INSLOTS) {
            int ci = id / (INH * SW);
            int rem = id - ci * (INH * SW);
            int r = rem / SW, cc = rem - r * SW;
            sl[k] = (ci * INH + r) * INW + cc;
            int gy = by0 - 1 + r, gx = bx0 - 1 + cc;
            if (gy >= 0 && gy < H && gx >= 0 && gx < W)
                sg[k] = ci * HW + gy * W + gx;
        }
    }
    int wco = t / PARTS, wpart = t % PARTS;
    const float* wrun = w + (size_t)(co0 + wco) * 2304;   // 256*9 per out-channel

    float acc[COPT][4];
#pragma unroll
    for (int c = 0; c < COPT; ++c)
#pragma unroll
        for (int i = 0; i < 4; ++i) acc[c][i] = 0.f;

    float* s_in_flat = &s_in[0][0][0];
    for (int ch = 0; ch < 32; ++ch) {
        const float* sb = src + (size_t)(ch * 8) * HW;
        const float* wr = wrun + ch * 72;
#pragma unroll
        for (int k = 0; k < KSTG; ++k)
            if (sl[k] >= 0)
                s_in_flat[sl[k]] = (sg[k] >= 0) ? sb[sg[k]] : 0.f;
#pragma unroll
        for (int k = 0; k < EPT; ++k) {
            int e = wpart + PARTS * k;     // e = ci*9+tap, 0..71
            s_w[e * TCO + wco] = wr[e];
        }
        __syncthreads();
        for (int ci = 0; ci < 8; ++ci) {
            float inr[3][6];
#pragma unroll
            for (int ky = 0; ky < 3; ++ky)
#pragma unroll
                for (int j = 0; j < 6; ++j)
                    inr[ky][j] = s_in[ci][yr + ky][x0 + j];
            const float* wrow = &s_w[ci * 9 * TCO];
#pragma unroll
            for (int ky = 0; ky < 3; ++ky) {
#pragma unroll
                for (int kx = 0; kx < 3; ++kx) {
#pragma unroll
                    for (int c = 0; c < COPT; ++c) {
                        float wv = wrow[(ky * 3 + kx) * TCO + cg * COPT + c];
#pragma unroll
                        for (int i = 0; i < 4; ++i)
                            acc[c][i] += wv * inr[ky][kx + i];
                    }
                }
            }
        }
        __syncthreads();
    }
    int y = by0 + yr;
#pragma unroll
    for (int c = 0; c < COPT; ++c) {
        int co = co0 + cg * COPT + c;
        float bb = bias[co];
#pragma unroll
        for (int i = 0; i < 4; ++i) {
            int x = bx0 + x0 + i;
            if (x < W && y < H) {
                float v = acc[c][i] + bb;
                if (act) v = (v >= 0.f) ? v : 0.1f * v;
                dst[(size_t)co * HW + y * W + x] = v;
            }
        }
    }
}

// ---------------- decode: scores, argmax, boxes, sort keys ----------------
__launch_bounds__(256)
__global__ void decode_kernel(const float* __restrict__ cls, const float* __restrict__ reg,
                              const float* __restrict__ ctn, float* __restrict__ out,
                              unsigned long long* __restrict__ keys)
{
    int p = blockIdx.x * 256 + threadIdx.x;
    if (p >= 16384) return;
    if (p >= 8400) { keys[p] = ~0ull; return; }
    int base, hs; float s;
    if (p < 6400)      { base = 0;    hs = 80; s = 8.f;  }
    else if (p < 8000) { base = 6400; hs = 40; s = 16.f; }
    else               { base = 8000; hs = 20; s = 32.f; }
    int local = p - base;
    float gx = (float)(local % hs), gy = (float)(local / hs);
    float ct = ctn[p];
    float sct = 1.f / (1.f + expf(-ct));
    float best = -1.f; int arg = 0;
    for (int c = 0; c < 80; ++c) {
        float v = cls[(size_t)c * 8400 + p];
        float sv = 1.f / (1.f + expf(-v));
        float sc = sqrtf(sv * sct);
        if (sc > best) { best = sc; arg = c; }
    }
    float r0 = reg[0 * 8400 + p], r1 = reg[1 * 8400 + p];
    float r2 = reg[2 * 8400 + p], r3 = reg[3 * 8400 + p];
    float x1 = (gx - expf(r0)) * s / 640.f;
    float y1 = (gy - expf(r1)) * s / 640.f;
    float x2 = (gx + expf(r2)) * s / 640.f;
    float y2 = (gy + expf(r3)) * s / 640.f;
    x1 = fminf(fmaxf(x1, 0.f), 1.f);
    y1 = fminf(fmaxf(y1, 0.f), 1.f);
    x2 = fminf(fmaxf(x2, 0.f), 1.f);
    y2 = fminf(fmaxf(y2, 0.f), 1.f);
    out[p * 4 + 0] = x1; out[p * 4 + 1] = y1;
    out[p * 4 + 2] = x2; out[p * 4 + 3] = y2;
    out[33600 + p] = best;
    out[42000 + p] = (float)arg;
    out[50400 + p] = 0.f;     // keep init
    unsigned int ub = __float_as_uint(best);
    keys[p] = ((unsigned long long)(~ub) << 32) | (unsigned int)p;
}

// ---------------- hybrid bitonic sort of 16384 u64 keys ----------------
__launch_bounds__(256)
__global__ void bitonic_local(unsigned long long* __restrict__ keys, unsigned kmerge)
{
    __shared__ unsigned long long sk[2048];
    int t = threadIdx.x;
    unsigned base = blockIdx.x * 2048u;
#pragma unroll
    for (int m = 0; m < 8; ++m) sk[t + m * 256] = keys[base + t + m * 256];
    __syncthreads();
    if (kmerge == 0u) {
        for (unsigned k = 2; k <= 2048u; k <<= 1) {
            for (unsigned j = k >> 1; j > 0; j >>= 1) {
#pragma unroll
                for (int pp = 0; pp < 4; ++pp) {
                    unsigned p = (unsigned)t + pp * 256u;
                    unsigned li = ((p & ~(j - 1)) << 1) | (p & (j - 1));
                    unsigned gi = base + li;
                    bool up = ((gi & k) == 0);
                    unsigned long long a = sk[li], b = sk[li + j];
                    if ((a > b) == up) { sk[li] = b; sk[li + j] = a; }
                }
                __syncthreads();
            }
        }
    } else {
        unsigned k = kmerge;
        for (unsigned j = 1024; j > 0; j >>= 1) {
#pragma unroll
            for (int pp = 0; pp < 4; ++pp) {
                unsigned p = (unsigned)t + pp * 256u;
                unsigned li = ((p & ~(j - 1)) << 1) | (p & (j - 1));
                unsigned gi = base + li;
                bool up = ((gi & k) == 0);
                unsigned long long a = sk[li], b = sk[li + j];
                if ((a > b) == up) { sk[li] = b; sk[li + j] = a; }
            }
            __syncthreads();
        }
    }
#pragma unroll
    for (int m = 0; m < 8; ++m) keys[base + t + m * 256] = sk[t + m * 256];
}

__launch_bounds__(256)
__global__ void bitonic_global(unsigned long long* __restrict__ keys, unsigned k, unsigned j)
{
    unsigned p = blockIdx.x * 256u + threadIdx.x;
    unsigned i = ((p & ~(j - 1)) << 1) | (p & (j - 1));
    bool up = ((i & k) == 0);
    unsigned long long a = keys[i], b = keys[i + j];
    if ((a > b) == up) { keys[i] = b; keys[i + j] = a; }
}

// ---------------- expand sorted keys into SoA arrays ----------------
__launch_bounds__(256)
__global__ void sorted_aux(const unsigned long long* __restrict__ keys,
                           const float* __restrict__ out,
                           float* __restrict__ scs, int* __restrict__ clss,
                           int* __restrict__ idxs)
{
    int i = blockIdx.x * 256 + threadIdx.x;
    if (i >= 16384) return;
    unsigned long long key = keys[i];
    unsigned ub = ~(unsigned)(key >> 32);
    float sc = __uint_as_float(ub);
    unsigned idx = (unsigned)(key & 0xffffffffu);
    int cl = -1;
    if (idx < 8400u) cl = (int)out[42000 + idx];
    else sc = 0.f;
    scs[i] = sc; clss[i] = cl; idxs[i] = (int)idx;
}

// ---------------- NMS stage 1: per-class stable compaction ----------------
__launch_bounds__(256)
__global__ void compact_cls(const float* __restrict__ scs, const int* __restrict__ clss,
                            const int* __restrict__ idxs, const float* __restrict__ outbuf,
                            float* __restrict__ GX1, float* __restrict__ GY1,
                            float* __restrict__ GX2, float* __restrict__ GY2,
                            float* __restrict__ GAR, int* __restrict__ GIX,
                            int* __restrict__ NCOUNT, int* __restrict__ NBASE)
{
    int c = blockIdx.x, t = threadIdx.x;
    __shared__ int s_red[2];
    __shared__ int s_wtot[4];
    int cb = 0, co = 0;
    for (int i = t; i < 16384; i += 256) {
        float sc = scs[i]; int cl = clss[i];
        if (sc >= CONF_T && cl >= 0) { cb += (cl < c); co += (cl == c); }
    }
    if (t == 0) { s_red[0] = 0; s_red[1] = 0; }
    __syncthreads();
    atomicAdd(&s_red[0], cb);
    atomicAdd(&s_red[1], co);
    __syncthreads();
    int base = s_red[0], n = s_red[1];
    if (t == 0) { NCOUNT[c] = n; NBASE[c] = base; }

    int rank = 0;
    for (int st = 0; st < 16384; st += 256) {
        int i = st + t;
        float sc = scs[i]; int cl = clss[i];
        bool flag = (sc >= CONF_T && cl == c);
        unsigned long long m = __ballot(flag);
        int lane = t & 63, wv = t >> 6;
        if (lane == 0) s_wtot[wv] = __popcll(m);
        __syncthreads();
        int off = rank;
        for (int w = 0; w < wv; ++w) off += s_wtot[w];
        int tot = s_wtot[0] + s_wtot[1] + s_wtot[2] + s_wtot[3];
        if (flag) {
            int pos = off + __popcll(m & ((1ull << lane) - 1ull));
            int idx = idxs[i];
            float x1 = outbuf[idx * 4 + 0], y1 = outbuf[idx * 4 + 1];
            float x2 = outbuf[idx * 4 + 2], y2 = outbuf[idx * 4 + 3];
            GX1[base + pos] = x1; GY1[base + pos] = y1;
            GX2[base + pos] = x2; GY2[base + pos] = y2;
            GAR[base + pos] = (x2 - x1) * (y2 - y1);
            GIX[base + pos] = idx;
        }
        rank += tot;
        __syncthreads();
    }
}

// ---------------- NMS stage 2: suppression bit-matrix (parallel) ----------------
__launch_bounds__(256)
__global__ void nms_mask(const float* __restrict__ GX1, const float* __restrict__ GY1,
                         const float* __restrict__ GX2, const float* __restrict__ GY2,
                         const float* __restrict__ GAR,
                         const int* __restrict__ NCOUNT, const int* __restrict__ NBASE,
                         unsigned long long* __restrict__ MASK)
{
    int c = blockIdx.y;
    int n = NCOUNT[c];
    if ((int)(blockIdx.x * 256) >= n) return;
    int base = NBASE[c];
    int t = threadIdx.x;
    int r = blockIdx.x * 256 + t;
    bool hav = (r < n);
    float rx1 = 0.f, ry1 = 0.f, rx2 = 0.f, ry2 = 0.f, rar = 0.f;
    if (hav) {
        rx1 = GX1[base + r]; ry1 = GY1[base + r];
        rx2 = GX2[base + r]; ry2 = GY2[base + r];
        rar = GAR[base + r];
    }
    __shared__ float tx1[2048], ty1[2048], tx2[2048], ty2[2048], tar[2048];
    for (int jt = 0; jt < n; jt += 2048) {
        int cnt = min(2048, n - jt);
        __syncthreads();
        for (int k = t; k < cnt; k += 256) {
            tx1[k] = GX1[base + jt + k]; ty1[k] = GY1[base + jt + k];
            tx2[k] = GX2[base + jt + k]; ty2[k] = GY2[base + jt + k];
            tar[k] = GAR[base + jt + k];
        }
        __syncthreads();
        if (hav) {
            int w0 = jt >> 6;
            int nw = (cnt + 63) >> 6;
            for (int w = 0; w < nw; ++w) {
                int jb = jt + w * 64;
                unsigned long long bits = 0ull;
                if (jb + 63 > r) {
                    int kmax = min(64, n - jb);
                    for (int kk = 0; kk < kmax; ++kk) {
                        int j = jb + kk;
                        if (j > r) {
                            int k2 = j - jt;
                            float xx1 = fmaxf(rx1, tx1[k2]);
                            float yy1 = fmaxf(ry1, ty1[k2]);
                            float xx2 = fminf(rx2, tx2[k2]);
                            float yy2 = fminf(ry2, ty2[k2]);
                            float ww = fmaxf(1e-28f, xx2 - xx1);
                            float hh = fmaxf(1e-28f, yy2 - yy1);
                            float inter = ww * hh;
                            float ovr = inter / (rar + tar[k2] - inter);
                            if (ovr > NMS_T) bits |= (1ull << kk);
                        }
                    }
                }
                MASK[(size_t)(base + r) * WMAX + w0 + w] = bits;
            }
        }
    }
}

// ---------------- NMS stage 3: chunked bitmask scan (80 blocks) ----------------
__launch_bounds__(256)
__global__ void nms_scan(const unsigned long long* __restrict__ MASK,
                         const int* __restrict__ GIX,
                         const int* __restrict__ NCOUNT, const int* __restrict__ NBASE,
                         float* __restrict__ keep)
{
    int c = blockIdx.x, t = threadIdx.x;
    int n = NCOUNT[c];
    if (n == 0) return;
    int base = NBASE[c];
    int Wc = (n + 63) >> 6;
    __shared__ unsigned long long remv[WMAX];
    __shared__ unsigned long long sld[32][WMAX];
    __shared__ unsigned int s_alive;
    for (int w = t; w < Wc; w += 256) remv[w] = 0ull;
    __syncthreads();
    for (int i0 = 0; i0 < n; i0 += 32) {
        int rows = min(32, n - i0);
        int tot = rows * Wc;
        for (int k = t; k < tot; k += 256) {
            int rr = k / Wc, w = k - rr * Wc;
            sld[rr][w] = MASK[(size_t)(base + i0 + rr) * WMAX + w];
        }
        __syncthreads();
        if (t == 0) {
            int wq = i0 >> 6, b0 = i0 & 63;
            unsigned long long lw = remv[wq];
            unsigned am = 0;
            for (int rr = 0; rr < rows; ++rr) {
                if (!((lw >> (b0 + rr)) & 1ull)) {
                    am |= (1u << rr);
                    lw |= sld[rr][wq];
                }
            }
            s_alive = am;
        }
        __syncthreads();
        unsigned am = s_alive;
        for (int w = t; w < Wc; w += 256) {
            unsigned long long acc = remv[w];
            unsigned m = am;
            while (m) { int rr = __ffs(m) - 1; m &= m - 1; acc |= sld[rr][w]; }
            remv[w] = acc;
        }
        if (t < rows && ((am >> t) & 1u)) keep[GIX[base + i0 + t]] = 1.0f;
        __syncthreads();
    }
}

// ---------------- host orchestration ----------------
extern "C" void kernel_launch(void* const* d_in, const int* in_sizes, int n_in,
                              void* d_out, int out_size, void* d_ws, size_t ws_size,
                              hipStream_t stream)
{
    const float* c3      = (const float*)d_in[0];
    const float* c4      = (const float*)d_in[1];
    const float* c5      = (const float*)d_in[2];
    const float* lat1_w  = (const float*)d_in[3];
    const float* lat1_b  = (const float*)d_in[4];
    const float* lat2_w  = (const float*)d_in[5];
    const float* lat2_b  = (const float*)d_in[6];
    const float* lat3_w  = (const float*)d_in[7];
    const float* lat3_b  = (const float*)d_in[8];
    const float* sm1_w   = (const float*)d_in[9];
    const float* sm1_b   = (const float*)d_in[10];
    const float* sm2_w   = (const float*)d_in[11];
    const float* sm2_b   = (const float*)d_in[12];
    const float* sm3_w   = (const float*)d_in[13];
    const float* sm3_b   = (const float*)d_in[14];
    const float* clsh_w  = (const float*)d_in[15];
    const float* clsh_b  = (const float*)d_in[16];
    const float* regh_w  = (const float*)d_in[17];
    const float* regh_b  = (const float*)d_in[18];
    const float* clsd_w  = (const float*)d_in[19];
    const float* clsd_b  = (const float*)d_in[20];
    const float* regd_w  = (const float*)d_in[21];
    const float* regd_b  = (const float*)d_in[22];
    const float* ctnd_w  = (const float*)d_in[23];
    const float* ctnd_b  = (const float*)d_in[24];

    float* ws = (float*)d_ws;
    float* T3 = ws + OFF_T3;  float* T4 = ws + OFF_T4;  float* T5 = ws + OFF_T5;
    float* P3 = ws + OFF_P3;  float* P4 = ws + OFF_P4;  float* P5 = ws + OFF_P5;
    float* HA3 = ws + OFF_HA3; float* HA4 = ws + OFF_HA4; float* HA5 = ws + OFF_HA5;
    float* HB3 = ws + OFF_HB3; float* HB4 = ws + OFF_HB4; float* HB5 = ws + OFF_HB5;
    float* HD3 = ws + OFF_HD3; float* HD4 = ws + OFF_HD4; float* HD5 = ws + OFF_HD5;
    float* CLS = ws + OFF_CLS; float* REG = ws + OFF_REG; float* CTN = ws + OFF_CTN;
    unsigned long long* KEYS = (unsigned long long*)(ws + POFF_KEYS);
    float* SCS = ws + POFF_SCS;
    int* CLSS = (int*)(ws + POFF_CLSS);
    int* IDXS = (int*)(ws + POFF_IDXS);
    float* GX1 = ws + POFF_GX1; float* GY1 = ws + POFF_GY1;
    float* GX2 = ws + POFF_GX2; float* GY2 = ws + POFF_GY2;
    float* GAR = ws + POFF_GAR;
    int* GIX = (int*)(ws + POFF_GIX);
    int* NCOUNT = (int*)(ws + POFF_NCNT);
    int* NBASE  = (int*)(ws + POFF_NBASE);
    unsigned long long* MASK = (unsigned long long*)(ws + POFF_MASK);

    float* out = (float*)d_out;
    dim3 blk(256);
    const size_t WSTEP = 256u * 256u * 9u;

    // ---- FPN ----
    conv1x1_kernel<<<dim3(7, 4), blk, 0, stream>>>(c5, lat3_w, lat3_b, T5, nullptr,
                                                   512, 256, 400, 20, 400, 0);
    conv3x3_t<8, 4, 32><<<dim3(15, 8, 1), blk, 0, stream>>>(T5, T5, sm3_w, sm3_w, sm3_b, sm3_b,
                                                            P5, P5, 20, 20, 0);
    conv1x1_kernel<<<dim3(25, 4), blk, 0, stream>>>(c4, lat2_w, lat2_b, T4, T5,
                                                    256, 256, 1600, 40, 1600, 0);
    conv3x3_t<16, 4, 32><<<dim3(30, 8, 1), blk, 0, stream>>>(T4, T4, sm2_w, sm2_w, sm2_b, sm2_b,
                                                             P4, P4, 40, 40, 0);
    conv1x1_kernel<<<dim3(100, 4), blk, 0, stream>>>(c3, lat1_w, lat1_b, T3, T4,
                                                     128, 256, 6400, 80, 6400, 0);
    conv3x3_t<16, 8, 32><<<dim3(50, 8, 1), blk, 0, stream>>>(T3, T3, sm1_w, sm1_w, sm1_b, sm1_b,
                                                             P3, P3, 80, 80, 0);

    // ---- heads ----
    // L3 (80x80)
    {
        float* ping[2][5] = { {P3, HA3, HB3, HA3, HB3},
                              {P3, T3,  HD3, T3,  HD3} };
        for (int i = 0; i < 4; ++i) {
            conv3x3_t<16, 8, 32><<<dim3(50, 8, 2), blk, 0, stream>>>(
                ping[0][i], ping[1][i],
                clsh_w + (size_t)i * WSTEP, regh_w + (size_t)i * WSTEP,
                clsh_b + i * 256, regh_b + i * 256,
                ping[0][i + 1], ping[1][i + 1], 80, 80, 1);
        }
        conv1x1_kernel<<<dim3(100, 2), blk, 0, stream>>>(HB3, clsd_w, clsd_b, CLS, nullptr,
                                                         256, 80, 6400, 80, 8400, 0);
        conv1x1_kernel<<<dim3(100, 1), blk, 0, stream>>>(HD3, regd_w, regd_b, REG, nullptr,
                                                         256, 4, 6400, 80, 8400, 0);
        conv1x1_kernel<<<dim3(100, 1), blk, 0, stream>>>(HD3, ctnd_w, ctnd_b, CTN, nullptr,
                                                         256, 1, 6400, 80, 8400, 0);
    }
    // L4 (40x40)
    {
        float* ping[2][5] = { {P4, HA4, HB4, HA4, HB4},
                              {P4, T4,  HD4, T4,  HD4} };
        for (int i = 0; i < 4; ++i) {
            conv3x3_t<16, 4, 32><<<dim3(30, 8, 2), blk, 0, stream>>>(
                ping[0][i], ping[1][i],
                clsh_w + (size_t)i * WSTEP, regh_w + (size_t)i * WSTEP,
                clsh_b + i * 256, regh_b + i * 256,
                ping[0][i + 1], ping[1][i + 1], 40, 40, 1);
        }
        conv1x1_kernel<<<dim3(25, 2), blk, 0, stream>>>(HB4, clsd_w, clsd_b, CLS, nullptr,
                                                        256, 80, 1600, 40, 8400, 6400);
        conv1x1_kernel<<<dim3(25, 1), blk, 0, stream>>>(HD4, regd_w, regd_b, REG, nullptr,
                                                        256, 4, 1600, 40, 8400, 6400);
        conv1x1_kernel<<<dim3(25, 1), blk, 0, stream>>>(HD4, ctnd_w, ctnd_b, CTN, nullptr,
                                                        256, 1, 1600, 40, 8400, 6400);
    }
    // L5 (20x20)
    {
        float* ping[2][5] = { {P5, HA5, HB5, HA5, HB5},
                              {P5, T5,  HD5, T5,  HD5} };
        for (int i = 0; i < 4; ++i) {
            conv3x3_t<8, 4, 32><<<dim3(15, 8, 2), blk, 0, stream>>>(
                ping[0][i], ping[1][i],
                clsh_w + (size_t)i * WSTEP, regh_w + (size_t)i * WSTEP,
                clsh_b + i * 256, regh_b + i * 256,
                ping[0][i + 1], ping[1][i + 1], 20, 20, 1);
        }
        conv1x1_kernel<<<dim3(7, 2), blk, 0, stream>>>(HB5, clsd_w, clsd_b, CLS, nullptr,
                                                       256, 80, 400, 20, 8400, 8000);
        conv1x1_kernel<<<dim3(7, 1), blk, 0, stream>>>(HD5, regd_w, regd_b, REG, nullptr,
                                                       256, 4, 400, 20, 8400, 8000);
        conv1x1_kernel<<<dim3(7, 1), blk, 0, stream>>>(HD5, ctnd_w, ctnd_b, CTN, nullptr,
                                                       256, 1, 400, 20, 8400, 8000);
    }

    // ---- decode ----
    decode_kernel<<<dim3(64), blk, 0, stream>>>(CLS, REG, CTN, out, KEYS);

    // ---- hybrid bitonic sort ----
    bitonic_local<<<dim3(8), blk, 0, stream>>>(KEYS, 0u);
    bitonic_global<<<dim3(32), blk, 0, stream>>>(KEYS, 4096u, 2048u);
    bitonic_local<<<dim3(8), blk, 0, stream>>>(KEYS, 4096u);
    bitonic_global<<<dim3(32), blk, 0, stream>>>(KEYS, 8192u, 4096u);
    bitonic_global<<<dim3(32), blk, 0, stream>>>(KEYS, 8192u, 2048u);
    bitonic_local<<<dim3(8), blk, 0, stream>>>(KEYS, 8192u);
    bitonic_global<<<dim3(32), blk, 0, stream>>>(KEYS, 16384u, 8192u);
    bitonic_global<<<dim3(32), blk, 0, stream>>>(KEYS, 16384u, 4096u);
    bitonic_global<<<dim3(32), blk, 0, stream>>>(KEYS, 16384u, 2048u);
    bitonic_local<<<dim3(8), blk, 0, stream>>>(KEYS, 16384u);

    // ---- NMS pipeline ----
    sorted_aux<<<dim3(64), blk, 0, stream>>>(KEYS, out, SCS, CLSS, IDXS);
    compact_cls<<<dim3(80), blk, 0, stream>>>(SCS, CLSS, IDXS, out,
                                              GX1, GY1, GX2, GY2, GAR, GIX, NCOUNT, NBASE);
    nms_mask<<<dim3(33, 80), blk, 0, stream>>>(GX1, GY1, GX2, GY2, GAR, NCOUNT, NBASE, MASK);
    nms_scan<<<dim3(80), blk, 0, stream>>>(MASK, GIX, NCOUNT, NBASE, out + 50400);
}

// Round 5
// 2453.392 us; speedup vs baseline: 2.5732x; 1.4031x over previous
//
#include <hip/hip_runtime.h>
#include <stdint.h>

#define CONF_T 0.05f
#define NMS_T  0.5f
#define WMAX   132           // ceil(8400/64)

// ---- workspace layout (float offsets) ----
#define OFF_T3   0u
#define OFF_T4   1638400u
#define OFF_T5   2048000u
#define OFF_P3   2150400u
#define OFF_P4   3788800u
#define OFF_P5   4198400u
#define OFF_HA3  4300800u
#define OFF_HA4  5939200u
#define OFF_HA5  6348800u
#define OFF_HB3  6451200u
#define OFF_HB4  8089600u
#define OFF_HB5  8499200u
#define OFF_HD3  8601600u
#define OFF_HD4  10240000u
#define OFF_HD5  10649600u
#define OFF_CLS  10752000u
#define OFF_REG  11424000u
#define OFF_CTN  11457600u
// post-processing arrays (T3 region, free after conv stack)
#define POFF_KEYS  (OFF_T3 + 0u)
#define POFF_SCS   (OFF_T3 + 32768u)
#define POFF_CLSS  (OFF_T3 + 49152u)
#define POFF_IDXS  (OFF_T3 + 65536u)
#define POFF_GX1   (OFF_T3 + 81920u)
#define POFF_GY1   (OFF_T3 + 90320u)
#define POFF_GX2   (OFF_T3 + 98720u)
#define POFF_GY2   (OFF_T3 + 107120u)
#define POFF_GAR   (OFF_T3 + 115520u)
#define POFF_GIX   (OFF_T3 + 123920u)
#define POFF_NCNT  (OFF_T3 + 132320u)
#define POFF_NBASE (OFF_T3 + 132400u)
#define POFF_MASK  OFF_HA3

// ---------------- conv 1x1 (+ optional nearest-up2 add) ----------------
__launch_bounds__(256)
__global__ void conv1x1_kernel(const float* __restrict__ in, const float* __restrict__ w,
                               const float* __restrict__ b, float* __restrict__ out,
                               const float* __restrict__ add,
                               int Cin, int Cout, int NPX, int W, int outStride, int outBase)
{
    __shared__ float s_in[16][64];
    __shared__ float s_w[16][64];
    int t = threadIdx.x;
    int pxg = t & 31, cg = t >> 5;
    int px0 = blockIdx.x * 64;
    int co0 = blockIdx.y * 64;
    float acc[8][2];
#pragma unroll
    for (int c = 0; c < 8; ++c) { acc[c][0] = 0.f; acc[c][1] = 0.f; }
    int chunks = Cin >> 4;
    int wco = t >> 2, wpart = t & 3;
    for (int ch = 0; ch < chunks; ++ch) {
        int ci0 = ch << 4;
#pragma unroll
        for (int k = 0; k < 4; ++k) {
            int id = t + k * 256;
            int ci = id >> 6, pp = id & 63;
            int gp = px0 + pp;
            s_in[ci][pp] = (gp < NPX) ? in[(size_t)(ci0 + ci) * NPX + gp] : 0.f;
        }
        {
            int gco = co0 + wco;
            if (gco < Cout) {
                const float* run = w + (size_t)gco * Cin + ci0;
#pragma unroll
                for (int k = 0; k < 4; ++k) {
                    int e = wpart + 4 * k;
                    s_w[e][wco] = run[e];
                }
            } else {
#pragma unroll
                for (int k = 0; k < 4; ++k) s_w[wpart + 4 * k][wco] = 0.f;
            }
        }
        __syncthreads();
#pragma unroll
        for (int ci = 0; ci < 16; ++ci) {
            float i0 = s_in[ci][pxg * 2], i1 = s_in[ci][pxg * 2 + 1];
#pragma unroll
            for (int c = 0; c < 8; ++c) {
                float wv = s_w[ci][cg * 8 + c];
                acc[c][0] += wv * i0;
                acc[c][1] += wv * i1;
            }
        }
        __syncthreads();
    }
    for (int c = 0; c < 8; ++c) {
        int co = co0 + cg * 8 + c;
        if (co >= Cout) break;
        float bb = b[co];
#pragma unroll
        for (int j = 0; j < 2; ++j) {
            int p = px0 + pxg * 2 + j;
            if (p < NPX) {
                float v = acc[c][j] + bb;
                if (add) {
                    int y = p / W, x = p % W;
                    int Sp = W >> 1;
                    v += add[(size_t)co * (Sp * Sp) + (y >> 1) * Sp + (x >> 1)];
                }
                out[(size_t)co * outStride + outBase + p] = v;
            }
        }
    }
}

// ---------------- conv 3x3 body (shared by smooth + fused heads) ----------------
// INW = TW+5 (odd stride -> read banks conflict-free). Weight staging uses
// wco = t % TCO so a half-wave's 32 lanes hit 32 distinct banks (was 8-way).
// Double-buffered LDS, T14 split: load(ch+1)->regs, compute(ch), write LDS, 1 barrier.
template<int TW, int TH, int TCO>
__device__ __forceinline__ void conv3x3_body(
    const float* __restrict__ src, const float* __restrict__ w,
    const float* __restrict__ bias, float* __restrict__ dst,
    int H, int W, int act, int bx0, int by0, int co0,
    float* __restrict__ sin0, float* __restrict__ sin1,
    float* __restrict__ sw0, float* __restrict__ sw1)
{
    constexpr int TPX  = TW * TH;
    constexpr int NXQ  = TW / 4;
    constexpr int PXGN = TPX / 4;
    constexpr int COG  = 256 / PXGN;
    constexpr int COPT = TCO / COG;
    constexpr int INW  = TW + 5;
    constexpr int INH  = TH + 2;
    constexpr int SW   = TW + 2;
    constexpr int INSLOTS = 8 * INH * SW;
    constexpr int KSTG = (INSLOTS + 255) / 256;
    constexpr int EPT  = 72 * TCO / 256;      // 9 for TCO=32

    int t = threadIdx.x;
    int pxg = t % PXGN, cg = t / PXGN;
    int xq = pxg % NXQ, yr = pxg / NXQ;
    int x0 = xq * 4;
    int HW = H * W;

    // ch-invariant staging descriptors
    int sl[KSTG], sg[KSTG];
#pragma unroll
    for (int k = 0; k < KSTG; ++k) {
        int id = t + k * 256;
        sl[k] = -1; sg[k] = -1;
        if (id < INSLOTS) {
            int ci = id / (INH * SW);
            int rem = id - ci * (INH * SW);
            int r = rem / SW, cc = rem - r * SW;
            sl[k] = (ci * INH + r) * INW + cc;
            int gy = by0 - 1 + r, gx = bx0 - 1 + cc;
            if (gy >= 0 && gy < H && gx >= 0 && gx < W)
                sg[k] = ci * HW + gy * W + gx;
        }
    }
    int wco = t % TCO;          // lanes -> distinct banks on LDS writes
    int wpart = t / TCO;        // 0..7, each stages 9 consecutive weight elems
    const float* wbase = w + (size_t)(co0 + wco) * 2304;

    float acc[COPT][4];
#pragma unroll
    for (int c = 0; c < COPT; ++c)
#pragma unroll
        for (int i = 0; i < 4; ++i) acc[c][i] = 0.f;

    // stage chunk 0 directly
    {
#pragma unroll
        for (int k = 0; k < KSTG; ++k)
            if (sl[k] >= 0) sin0[sl[k]] = (sg[k] >= 0) ? src[sg[k]] : 0.f;
#pragma unroll
        for (int k = 0; k < EPT; ++k) {
            int e = wpart * EPT + k;
            sw0[e * TCO + wco] = wbase[e];
        }
    }
    __syncthreads();

    for (int ch = 0; ch < 32; ++ch) {
        float* cin = (ch & 1) ? sin1 : sin0;
        float* cw  = (ch & 1) ? sw1  : sw0;
        float vin[KSTG]; float vw[EPT];
        bool pf = (ch < 31);
        if (pf) {
            const float* sb = src + (size_t)((ch + 1) * 8) * HW;
            const float* wr = wbase + (ch + 1) * 72;
#pragma unroll
            for (int k = 0; k < KSTG; ++k)
                vin[k] = (sg[k] >= 0) ? sb[sg[k]] : 0.f;
#pragma unroll
            for (int k = 0; k < EPT; ++k)
                vw[k] = wr[wpart * EPT + k];
        }
        // compute chunk ch
        for (int ci = 0; ci < 8; ++ci) {
            float inr[3][6];
#pragma unroll
            for (int ky = 0; ky < 3; ++ky)
#pragma unroll
                for (int j = 0; j < 6; ++j)
                    inr[ky][j] = cin[(ci * INH + yr + ky) * INW + x0 + j];
            const float* wrow = cw + ci * 9 * TCO;
#pragma unroll
            for (int ky = 0; ky < 3; ++ky) {
#pragma unroll
                for (int kx = 0; kx < 3; ++kx) {
#pragma unroll
                    for (int c = 0; c < COPT; ++c) {
                        float wv = wrow[(ky * 3 + kx) * TCO + cg * COPT + c];
#pragma unroll
                        for (int i = 0; i < 4; ++i)
                            acc[c][i] += wv * inr[ky][kx + i];
                    }
                }
            }
        }
        if (pf) {
            float* nin = (ch & 1) ? sin0 : sin1;
            float* nw  = (ch & 1) ? sw0  : sw1;
#pragma unroll
            for (int k = 0; k < KSTG; ++k)
                if (sl[k] >= 0) nin[sl[k]] = vin[k];
#pragma unroll
            for (int k = 0; k < EPT; ++k) {
                int e = wpart * EPT + k;
                nw[e * TCO + wco] = vw[k];
            }
        }
        __syncthreads();
    }

    int y = by0 + yr;
#pragma unroll
    for (int c = 0; c < COPT; ++c) {
        int co = co0 + cg * COPT + c;
        float bb = bias[co];
#pragma unroll
        for (int i = 0; i < 4; ++i) {
            int x = bx0 + x0 + i;
            if (x < W && y < H) {
                float v = acc[c][i] + bb;
                if (act) v = (v >= 0.f) ? v : 0.1f * v;
                dst[(size_t)co * HW + y * W + x] = v;
            }
        }
    }
}

// ---------------- smooth conv wrapper (single level) ----------------
template<int TW, int TH, int TCO>
__launch_bounds__(256)
__global__ void conv3x3_t(const float* __restrict__ src, const float* __restrict__ w,
                          const float* __restrict__ b, float* __restrict__ dst,
                          int H, int W, int act)
{
    constexpr int INW = TW + 5, INH = TH + 2;
    __shared__ float s_in[2][8 * INH * INW];
    __shared__ float s_w[2][72 * TCO];
    int nTx = (W + TW - 1) / TW;
    int tx = blockIdx.x % nTx, ty = blockIdx.x / nTx;
    conv3x3_body<TW, TH, TCO>(src, w, b, dst, H, W, act,
                              tx * TW, ty * TH, blockIdx.y * TCO,
                              s_in[0], s_in[1], s_w[0], s_w[1]);
}

// ---------------- fused 3-level head conv (one layer, both branches) ----------------
struct HeadPtrs {
    const float* src[2][3];
    float*       dst[2][3];
};

__launch_bounds__(256)
__global__ void conv3x3_heads(HeadPtrs hp, const float* __restrict__ wA,
                              const float* __restrict__ wB,
                              const float* __restrict__ bA, const float* __restrict__ bB)
{
    constexpr int TW = 16, TH = 8, TCO = 32;
    constexpr int INW = TW + 5, INH = TH + 2;
    __shared__ float s_in[2][8 * INH * INW];
    __shared__ float s_w[2][72 * TCO];

    int tb = blockIdx.x;                       // 0..70: 50 (L3) + 15 (L4) + 6 (L5)
    int lvl = (tb < 50) ? 0 : (tb < 65) ? 1 : 2;
    int tloc = tb - ((lvl == 0) ? 0 : (lvl == 1) ? 50 : 65);
    int W = (lvl == 0) ? 80 : (lvl == 1) ? 40 : 20;
    int br = blockIdx.z;
    const float* src = hp.src[br][lvl];
    float* dst = hp.dst[br][lvl];
    const float* w    = br ? wB : wA;
    const float* bias = br ? bB : bA;
    int nTx = (W + TW - 1) / TW;
    int tx = tloc % nTx, ty = tloc / nTx;
    conv3x3_body<TW, TH, TCO>(src, w, bias, dst, W, W, 1,
                              tx * TW, ty * TH, blockIdx.y * TCO,
                              s_in[0], s_in[1], s_w[0], s_w[1]);
}

// ---------------- decode: scores, argmax, boxes, sort keys ----------------
__launch_bounds__(256)
__global__ void decode_kernel(const float* __restrict__ cls, const float* __restrict__ reg,
                              const float* __restrict__ ctn, float* __restrict__ out,
                              unsigned long long* __restrict__ keys)
{
    int p = blockIdx.x * 256 + threadIdx.x;
    if (p >= 16384) return;
    if (p >= 8400) { keys[p] = ~0ull; return; }
    int base, hs; float s;
    if (p < 6400)      { base = 0;    hs = 80; s = 8.f;  }
    else if (p < 8000) { base = 6400; hs = 40; s = 16.f; }
    else               { base = 8000; hs = 20; s = 32.f; }
    int local = p - base;
    float gx = (float)(local % hs), gy = (float)(local / hs);
    float ct = ctn[p];
    float sct = 1.f / (1.f + expf(-ct));
    float best = -1.f; int arg = 0;
    for (int c = 0; c < 80; ++c) {
        float v = cls[(size_t)c * 8400 + p];
        float sv = 1.f / (1.f + expf(-v));
        float sc = sqrtf(sv * sct);
        if (sc > best) { best = sc; arg = c; }
    }
    float r0 = reg[0 * 8400 + p], r1 = reg[1 * 8400 + p];
    float r2 = reg[2 * 8400 + p], r3 = reg[3 * 8400 + p];
    float x1 = (gx - expf(r0)) * s / 640.f;
    float y1 = (gy - expf(r1)) * s / 640.f;
    float x2 = (gx + expf(r2)) * s / 640.f;
    float y2 = (gy + expf(r3)) * s / 640.f;
    x1 = fminf(fmaxf(x1, 0.f), 1.f);
    y1 = fminf(fmaxf(y1, 0.f), 1.f);
    x2 = fminf(fmaxf(x2, 0.f), 1.f);
    y2 = fminf(fmaxf(y2, 0.f), 1.f);
    out[p * 4 + 0] = x1; out[p * 4 + 1] = y1;
    out[p * 4 + 2] = x2; out[p * 4 + 3] = y2;
    out[33600 + p] = best;
    out[42000 + p] = (float)arg;
    out[50400 + p] = 0.f;
    unsigned int ub = __float_as_uint(best);
    keys[p] = ((unsigned long long)(~ub) << 32) | (unsigned int)p;
}

// ---------------- hybrid bitonic sort of 16384 u64 keys ----------------
__launch_bounds__(256)
__global__ void bitonic_local(unsigned long long* __restrict__ keys, unsigned kmerge)
{
    __shared__ unsigned long long sk[2048];
    int t = threadIdx.x;
    unsigned base = blockIdx.x * 2048u;
#pragma unroll
    for (int m = 0; m < 8; ++m) sk[t + m * 256] = keys[base + t + m * 256];
    __syncthreads();
    if (kmerge == 0u) {
        for (unsigned k = 2; k <= 2048u; k <<= 1) {
            for (unsigned j = k >> 1; j > 0; j >>= 1) {
#pragma unroll
                for (int pp = 0; pp < 4; ++pp) {
                    unsigned p = (unsigned)t + pp * 256u;
                    unsigned li = ((p & ~(j - 1)) << 1) | (p & (j - 1));
                    unsigned gi = base + li;
                    bool up = ((gi & k) == 0);
                    unsigned long long a = sk[li], b = sk[li + j];
                    if ((a > b) == up) { sk[li] = b; sk[li + j] = a; }
                }
                __syncthreads();
            }
        }
    } else {
        unsigned k = kmerge;
        for (unsigned j = 1024; j > 0; j >>= 1) {
#pragma unroll
            for (int pp = 0; pp < 4; ++pp) {
                unsigned p = (unsigned)t + pp * 256u;
                unsigned li = ((p & ~(j - 1)) << 1) | (p & (j - 1));
                unsigned gi = base + li;
                bool up = ((gi & k) == 0);
                unsigned long long a = sk[li], b = sk[li + j];
                if ((a > b) == up) { sk[li] = b; sk[li + j] = a; }
            }
            __syncthreads();
        }
    }
#pragma unroll
    for (int m = 0; m < 8; ++m) keys[base + t + m * 256] = sk[t + m * 256];
}

__launch_bounds__(256)
__global__ void bitonic_global(unsigned long long* __restrict__ keys, unsigned k, unsigned j)
{
    unsigned p = blockIdx.x * 256u + threadIdx.x;
    unsigned i = ((p & ~(j - 1)) << 1) | (p & (j - 1));
    bool up = ((i & k) == 0);
    unsigned long long a = keys[i], b = keys[i + j];
    if ((a > b) == up) { keys[i] = b; keys[i + j] = a; }
}

// ---------------- expand sorted keys into SoA arrays ----------------
__launch_bounds__(256)
__global__ void sorted_aux(const unsigned long long* __restrict__ keys,
                           const float* __restrict__ out,
                           float* __restrict__ scs, int* __restrict__ clss,
                           int* __restrict__ idxs)
{
    int i = blockIdx.x * 256 + threadIdx.x;
    if (i >= 16384) return;
    unsigned long long key = keys[i];
    unsigned ub = ~(unsigned)(key >> 32);
    float sc = __uint_as_float(ub);
    unsigned idx = (unsigned)(key & 0xffffffffu);
    int cl = -1;
    if (idx < 8400u) cl = (int)out[42000 + idx];
    else sc = 0.f;
    scs[i] = sc; clss[i] = cl; idxs[i] = (int)idx;
}

// ---------------- NMS stage 1: per-class stable compaction ----------------
__launch_bounds__(256)
__global__ void compact_cls(const float* __restrict__ scs, const int* __restrict__ clss,
                            const int* __restrict__ idxs, const float* __restrict__ outbuf,
                            float* __restrict__ GX1, float* __restrict__ GY1,
                            float* __restrict__ GX2, float* __restrict__ GY2,
                            float* __restrict__ GAR, int* __restrict__ GIX,
                            int* __restrict__ NCOUNT, int* __restrict__ NBASE)
{
    int c = blockIdx.x, t = threadIdx.x;
    __shared__ int s_red[2];
    __shared__ int s_wtot[4];
    int cb = 0, co = 0;
    for (int i = t; i < 16384; i += 256) {
        float sc = scs[i]; int cl = clss[i];
        if (sc >= CONF_T && cl >= 0) { cb += (cl < c); co += (cl == c); }
    }
    if (t == 0) { s_red[0] = 0; s_red[1] = 0; }
    __syncthreads();
    atomicAdd(&s_red[0], cb);
    atomicAdd(&s_red[1], co);
    __syncthreads();
    int base = s_red[0], n = s_red[1];
    if (t == 0) { NCOUNT[c] = n; NBASE[c] = base; }

    int rank = 0;
    for (int st = 0; st < 16384; st += 256) {
        int i = st + t;
        float sc = scs[i]; int cl = clss[i];
        bool flag = (sc >= CONF_T && cl == c);
        unsigned long long m = __ballot(flag);
        int lane = t & 63, wv = t >> 6;
        if (lane == 0) s_wtot[wv] = __popcll(m);
        __syncthreads();
        int off = rank;
        for (int w = 0; w < wv; ++w) off += s_wtot[w];
        int tot = s_wtot[0] + s_wtot[1] + s_wtot[2] + s_wtot[3];
        if (flag) {
            int pos = off + __popcll(m & ((1ull << lane) - 1ull));
            int idx = idxs[i];
            float x1 = outbuf[idx * 4 + 0], y1 = outbuf[idx * 4 + 1];
            float x2 = outbuf[idx * 4 + 2], y2 = outbuf[idx * 4 + 3];
            GX1[base + pos] = x1; GY1[base + pos] = y1;
            GX2[base + pos] = x2; GY2[base + pos] = y2;
            GAR[base + pos] = (x2 - x1) * (y2 - y1);
            GIX[base + pos] = idx;
        }
        rank += tot;
        __syncthreads();
    }
}

// ---------------- NMS stage 2: suppression bit-matrix (parallel) ----------------
__launch_bounds__(256)
__global__ void nms_mask(const float* __restrict__ GX1, const float* __restrict__ GY1,
                         const float* __restrict__ GX2, const float* __restrict__ GY2,
                         const float* __restrict__ GAR,
                         const int* __restrict__ NCOUNT, const int* __restrict__ NBASE,
                         unsigned long long* __restrict__ MASK)
{
    int c = blockIdx.y;
    int n = NCOUNT[c];
    if ((int)(blockIdx.x * 256) >= n) return;
    int base = NBASE[c];
    int t = threadIdx.x;
    int r = blockIdx.x * 256 + t;
    bool hav = (r < n);
    float rx1 = 0.f, ry1 = 0.f, rx2 = 0.f, ry2 = 0.f, rar = 0.f;
    if (hav) {
        rx1 = GX1[base + r]; ry1 = GY1[base + r];
        rx2 = GX2[base + r]; ry2 = GY2[base + r];
        rar = GAR[base + r];
    }
    __shared__ float tx1[2048], ty1[2048], tx2[2048], ty2[2048], tar[2048];
    for (int jt = 0; jt < n; jt += 2048) {
        int cnt = min(2048, n - jt);
        __syncthreads();
        for (int k = t; k < cnt; k += 256) {
            tx1[k] = GX1[base + jt + k]; ty1[k] = GY1[base + jt + k];
            tx2[k] = GX2[base + jt + k]; ty2[k] = GY2[base + jt + k];
            tar[k] = GAR[base + jt + k];
        }
        __syncthreads();
        if (hav) {
            int w0 = jt >> 6;
            int nw = (cnt + 63) >> 6;
            for (int w = 0; w < nw; ++w) {
                int jb = jt + w * 64;
                unsigned long long bits = 0ull;
                if (jb + 63 > r) {
                    int kmax = min(64, n - jb);
                    for (int kk = 0; kk < kmax; ++kk) {
                        int j = jb + kk;
                        if (j > r) {
                            int k2 = j - jt;
                            float xx1 = fmaxf(rx1, tx1[k2]);
                            float yy1 = fmaxf(ry1, ty1[k2]);
                            float xx2 = fminf(rx2, tx2[k2]);
                            float yy2 = fminf(ry2, ty2[k2]);
                            float ww = fmaxf(1e-28f, xx2 - xx1);
                            float hh = fmaxf(1e-28f, yy2 - yy1);
                            float inter = ww * hh;
                            float ovr = inter / (rar + tar[k2] - inter);
                            if (ovr > NMS_T) bits |= (1ull << kk);
                        }
                    }
                }
                MASK[(size_t)(base + r) * WMAX + w0 + w] = bits;
            }
        }
    }
}

// ---------------- NMS stage 3: chunked bitmask scan (80 blocks) ----------------
__launch_bounds__(256)
__global__ void nms_scan(const unsigned long long* __restrict__ MASK,
                         const int* __restrict__ GIX,
                         const int* __restrict__ NCOUNT, const int* __restrict__ NBASE,
                         float* __restrict__ keep)
{
    int c = blockIdx.x, t = threadIdx.x;
    int n = NCOUNT[c];
    if (n == 0) return;
    int base = NBASE[c];
    int Wc = (n + 63) >> 6;
    __shared__ unsigned long long remv[WMAX];
    __shared__ unsigned long long sld[32][WMAX];
    __shared__ unsigned int s_alive;
    for (int w = t; w < Wc; w += 256) remv[w] = 0ull;
    __syncthreads();
    for (int i0 = 0; i0 < n; i0 += 32) {
        int rows = min(32, n - i0);
        int tot = rows * Wc;
        for (int k = t; k < tot; k += 256) {
            int rr = k / Wc, w = k - rr * Wc;
            sld[rr][w] = MASK[(size_t)(base + i0 + rr) * WMAX + w];
        }
        __syncthreads();
        if (t == 0) {
            int wq = i0 >> 6, b0 = i0 & 63;
            unsigned long long lw = remv[wq];
            unsigned am = 0;
            for (int rr = 0; rr < rows; ++rr) {
                if (!((lw >> (b0 + rr)) & 1ull)) {
                    am |= (1u << rr);
                    lw |= sld[rr][wq];
                }
            }
            s_alive = am;
        }
        __syncthreads();
        unsigned am = s_alive;
        for (int w = t; w < Wc; w += 256) {
            unsigned long long acc = remv[w];
            unsigned m = am;
            while (m) { int rr = __ffs(m) - 1; m &= m - 1; acc |= sld[rr][w]; }
            remv[w] = acc;
        }
        if (t < rows && ((am >> t) & 1u)) keep[GIX[base + i0 + t]] = 1.0f;
        __syncthreads();
    }
}

// ---------------- host orchestration ----------------
extern "C" void kernel_launch(void* const* d_in, const int* in_sizes, int n_in,
                              void* d_out, int out_size, void* d_ws, size_t ws_size,
                              hipStream_t stream)
{
    const float* c3      = (const float*)d_in[0];
    const float* c4      = (const float*)d_in[1];
    const float* c5      = (const float*)d_in[2];
    const float* lat1_w  = (const float*)d_in[3];
    const float* lat1_b  = (const float*)d_in[4];
    const float* lat2_w  = (const float*)d_in[5];
    const float* lat2_b  = (const float*)d_in[6];
    const float* lat3_w  = (const float*)d_in[7];
    const float* lat3_b  = (const float*)d_in[8];
    const float* sm1_w   = (const float*)d_in[9];
    const float* sm1_b   = (const float*)d_in[10];
    const float* sm2_w   = (const float*)d_in[11];
    const float* sm2_b   = (const float*)d_in[12];
    const float* sm3_w   = (const float*)d_in[13];
    const float* sm3_b   = (const float*)d_in[14];
    const float* clsh_w  = (const float*)d_in[15];
    const float* clsh_b  = (const float*)d_in[16];
    const float* regh_w  = (const float*)d_in[17];
    const float* regh_b  = (const float*)d_in[18];
    const float* clsd_w  = (const float*)d_in[19];
    const float* clsd_b  = (const float*)d_in[20];
    const float* regd_w  = (const float*)d_in[21];
    const float* regd_b  = (const float*)d_in[22];
    const float* ctnd_w  = (const float*)d_in[23];
    const float* ctnd_b  = (const float*)d_in[24];

    float* ws = (float*)d_ws;
    float* T3 = ws + OFF_T3;  float* T4 = ws + OFF_T4;  float* T5 = ws + OFF_T5;
    float* P3 = ws + OFF_P3;  float* P4 = ws + OFF_P4;  float* P5 = ws + OFF_P5;
    float* HA3 = ws + OFF_HA3; float* HA4 = ws + OFF_HA4; float* HA5 = ws + OFF_HA5;
    float* HB3 = ws + OFF_HB3; float* HB4 = ws + OFF_HB4; float* HB5 = ws + OFF_HB5;
    float* HD3 = ws + OFF_HD3; float* HD4 = ws + OFF_HD4; float* HD5 = ws + OFF_HD5;
    float* CLS = ws + OFF_CLS; float* REG = ws + OFF_REG; float* CTN = ws + OFF_CTN;
    unsigned long long* KEYS = (unsigned long long*)(ws + POFF_KEYS);
    float* SCS = ws + POFF_SCS;
    int* CLSS = (int*)(ws + POFF_CLSS);
    int* IDXS = (int*)(ws + POFF_IDXS);
    float* GX1 = ws + POFF_GX1; float* GY1 = ws + POFF_GY1;
    float* GX2 = ws + POFF_GX2; float* GY2 = ws + POFF_GY2;
    float* GAR = ws + POFF_GAR;
    int* GIX = (int*)(ws + POFF_GIX);
    int* NCOUNT = (int*)(ws + POFF_NCNT);
    int* NBASE  = (int*)(ws + POFF_NBASE);
    unsigned long long* MASK = (unsigned long long*)(ws + POFF_MASK);

    float* out = (float*)d_out;
    dim3 blk(256);
    const size_t WSTEP = 256u * 256u * 9u;

    // ---- FPN ----
    conv1x1_kernel<<<dim3(7, 4), blk, 0, stream>>>(c5, lat3_w, lat3_b, T5, nullptr,
                                                   512, 256, 400, 20, 400, 0);
    conv3x3_t<8, 4, 32><<<dim3(15, 8), blk, 0, stream>>>(T5, sm3_w, sm3_b, P5, 20, 20, 0);
    conv1x1_kernel<<<dim3(25, 4), blk, 0, stream>>>(c4, lat2_w, lat2_b, T4, T5,
                                                    256, 256, 1600, 40, 1600, 0);
    conv3x3_t<16, 4, 32><<<dim3(30, 8), blk, 0, stream>>>(T4, sm2_w, sm2_b, P4, 40, 40, 0);
    conv1x1_kernel<<<dim3(100, 4), blk, 0, stream>>>(c3, lat1_w, lat1_b, T3, T4,
                                                     128, 256, 6400, 80, 6400, 0);
    conv3x3_t<16, 8, 32><<<dim3(50, 8), blk, 0, stream>>>(T3, sm1_w, sm1_b, P3, 80, 80, 0);

    // ---- heads: 4 fused layers, 3 levels + both branches per dispatch ----
    {
        float* clsS[3][5] = { {P3, HA3, HB3, HA3, HB3},
                              {P4, HA4, HB4, HA4, HB4},
                              {P5, HA5, HB5, HA5, HB5} };
        float* regS[3][5] = { {P3, T3,  HD3, T3,  HD3},
                              {P4, T4,  HD4, T4,  HD4},
                              {P5, T5,  HD5, T5,  HD5} };
        for (int i = 0; i < 4; ++i) {
            HeadPtrs hp;
            for (int l = 0; l < 3; ++l) {
                hp.src[0][l] = clsS[l][i];     hp.dst[0][l] = clsS[l][i + 1];
                hp.src[1][l] = regS[l][i];     hp.dst[1][l] = regS[l][i + 1];
            }
            conv3x3_heads<<<dim3(71, 8, 2), blk, 0, stream>>>(
                hp, clsh_w + (size_t)i * WSTEP, regh_w + (size_t)i * WSTEP,
                clsh_b + i * 256, regh_b + i * 256);
        }
    }

    // ---- detectors (1x1) ----
    conv1x1_kernel<<<dim3(100, 2), blk, 0, stream>>>(HB3, clsd_w, clsd_b, CLS, nullptr,
                                                     256, 80, 6400, 80, 8400, 0);
    conv1x1_kernel<<<dim3(100, 1), blk, 0, stream>>>(HD3, regd_w, regd_b, REG, nullptr,
                                                     256, 4, 6400, 80, 8400, 0);
    conv1x1_kernel<<<dim3(100, 1), blk, 0, stream>>>(HD3, ctnd_w, ctnd_b, CTN, nullptr,
                                                     256, 1, 6400, 80, 8400, 0);
    conv1x1_kernel<<<dim3(25, 2), blk, 0, stream>>>(HB4, clsd_w, clsd_b, CLS, nullptr,
                                                    256, 80, 1600, 40, 8400, 6400);
    conv1x1_kernel<<<dim3(25, 1), blk, 0, stream>>>(HD4, regd_w, regd_b, REG, nullptr,
                                                    256, 4, 1600, 40, 8400, 6400);
    conv1x1_kernel<<<dim3(25, 1), blk, 0, stream>>>(HD4, ctnd_w, ctnd_b, CTN, nullptr,
                                                    256, 1, 1600, 40, 8400, 6400);
    conv1x1_kernel<<<dim3(7, 2), blk, 0, stream>>>(HB5, clsd_w, clsd_b, CLS, nullptr,
                                                   256, 80, 400, 20, 8400, 8000);
    conv1x1_kernel<<<dim3(7, 1), blk, 0, stream>>>(HD5, regd_w, regd_b, REG, nullptr,
                                                   256, 4, 400, 20, 8400, 8000);
    conv1x1_kernel<<<dim3(7, 1), blk, 0, stream>>>(HD5, ctnd_w, ctnd_b, CTN, nullptr,
                                                   256, 1, 400, 20, 8400, 8000);

    // ---- decode ----
    decode_kernel<<<dim3(64), blk, 0, stream>>>(CLS, REG, CTN, out, KEYS);

    // ---- hybrid bitonic sort ----
    bitonic_local<<<dim3(8), blk, 0, stream>>>(KEYS, 0u);
    bitonic_global<<<dim3(32), blk, 0, stream>>>(KEYS, 4096u, 2048u);
    bitonic_local<<<dim3(8), blk, 0, stream>>>(KEYS, 4096u);
    bitonic_global<<<dim3(32), blk, 0, stream>>>(KEYS, 8192u, 4096u);
    bitonic_global<<<dim3(32), blk, 0, stream>>>(KEYS, 8192u, 2048u);
    bitonic_local<<<dim3(8), blk, 0, stream>>>(KEYS, 8192u);
    bitonic_global<<<dim3(32), blk, 0, stream>>>(KEYS, 16384u, 8192u);
    bitonic_global<<<dim3(32), blk, 0, stream>>>(KEYS, 16384u, 4096u);
    bitonic_global<<<dim3(32), blk, 0, stream>>>(KEYS, 16384u, 2048u);
    bitonic_local<<<dim3(8), blk, 0, stream>>>(KEYS, 16384u);

    // ---- NMS pipeline ----
    sorted_aux<<<dim3(64), blk, 0, stream>>>(KEYS, out, SCS, CLSS, IDXS);
    compact_cls<<<dim3(80), blk, 0, stream>>>(SCS, CLSS, IDXS, out,
                                              GX1, GY1, GX2, GY2, GAR, GIX, NCOUNT, NBASE);
    nms_mask<<<dim3(33, 80), blk, 0, stream>>>(GX1, GY1, GX2, GY2, GAR, NCOUNT, NBASE, MASK);
    nms_scan<<<dim3(80), blk, 0, stream>>>(MASK, GIX, NCOUNT, NBASE, out + 50400);
}

// Round 6
// 2265.549 us; speedup vs baseline: 2.7866x; 1.0829x over previous
//
#include <hip/hip_runtime.h>
#include <stdint.h>

#define CONF_T 0.05f
#define NMS_T  0.5f
#define WMAX   132           // ceil(8400/64)

// ---- workspace layout (float offsets) ----
#define OFF_T3   0u
#define OFF_T4   1638400u
#define OFF_T5   2048000u
#define OFF_P3   2150400u
#define OFF_P4   3788800u
#define OFF_P5   4198400u
#define OFF_HA3  4300800u
#define OFF_HA4  5939200u
#define OFF_HA5  6348800u
#define OFF_HB3  6451200u
#define OFF_HB4  8089600u
#define OFF_HB5  8499200u
#define OFF_HD3  8601600u
#define OFF_HD4  10240000u
#define OFF_HD5  10649600u
#define OFF_CLS  10752000u
#define OFF_REG  11424000u
#define OFF_CTN  11457600u
// post-processing arrays (T3 region, free after conv stack)
#define POFF_KEYS  (OFF_T3 + 0u)
#define POFF_SCS   (OFF_T3 + 32768u)
#define POFF_CLSS  (OFF_T3 + 49152u)
#define POFF_IDXS  (OFF_T3 + 65536u)
#define POFF_GX1   (OFF_T3 + 81920u)
#define POFF_GY1   (OFF_T3 + 90320u)
#define POFF_GX2   (OFF_T3 + 98720u)
#define POFF_GY2   (OFF_T3 + 107120u)
#define POFF_GAR   (OFF_T3 + 115520u)
#define POFF_GIX   (OFF_T3 + 123920u)
#define POFF_NCNT  (OFF_T3 + 132320u)
#define POFF_NBASE (OFF_T3 + 132400u)
#define POFF_MASK  OFF_HA3

// ---------------- conv 1x1 (+ optional nearest-up2 add) ----------------
__launch_bounds__(256)
__global__ void conv1x1_kernel(const float* __restrict__ in, const float* __restrict__ w,
                               const float* __restrict__ b, float* __restrict__ out,
                               const float* __restrict__ add,
                               int Cin, int Cout, int NPX, int W, int outStride, int outBase)
{
    __shared__ float s_in[16][64];
    __shared__ float s_w[16][64];
    int t = threadIdx.x;
    int pxg = t & 31, cg = t >> 5;
    int px0 = blockIdx.x * 64;
    int co0 = blockIdx.y * 64;
    float acc[8][2];
#pragma unroll
    for (int c = 0; c < 8; ++c) { acc[c][0] = 0.f; acc[c][1] = 0.f; }
    int chunks = Cin >> 4;
    int wco = t >> 2, wpart = t & 3;
    for (int ch = 0; ch < chunks; ++ch) {
        int ci0 = ch << 4;
#pragma unroll
        for (int k = 0; k < 4; ++k) {
            int id = t + k * 256;
            int ci = id >> 6, pp = id & 63;
            int gp = px0 + pp;
            s_in[ci][pp] = (gp < NPX) ? in[(size_t)(ci0 + ci) * NPX + gp] : 0.f;
        }
        {
            int gco = co0 + wco;
            if (gco < Cout) {
                const float* run = w + (size_t)gco * Cin + ci0;
#pragma unroll
                for (int k = 0; k < 4; ++k) {
                    int e = wpart + 4 * k;
                    s_w[e][wco] = run[e];
                }
            } else {
#pragma unroll
                for (int k = 0; k < 4; ++k) s_w[wpart + 4 * k][wco] = 0.f;
            }
        }
        __syncthreads();
#pragma unroll
        for (int ci = 0; ci < 16; ++ci) {
            float i0 = s_in[ci][pxg * 2], i1 = s_in[ci][pxg * 2 + 1];
#pragma unroll
            for (int c = 0; c < 8; ++c) {
                float wv = s_w[ci][cg * 8 + c];
                acc[c][0] += wv * i0;
                acc[c][1] += wv * i1;
            }
        }
        __syncthreads();
    }
    for (int c = 0; c < 8; ++c) {
        int co = co0 + cg * 8 + c;
        if (co >= Cout) break;
        float bb = b[co];
#pragma unroll
        for (int j = 0; j < 2; ++j) {
            int p = px0 + pxg * 2 + j;
            if (p < NPX) {
                float v = acc[c][j] + bb;
                if (add) {
                    int y = p / W, x = p % W;
                    int Sp = W >> 1;
                    v += add[(size_t)co * (Sp * Sp) + (y >> 1) * Sp + (x >> 1)];
                }
                out[(size_t)co * outStride + outBase + p] = v;
            }
        }
    }
}

// ---------------- fused detector 1x1 (9 combos in one dispatch) ----------------
struct Det9 {
    const float* src[9]; const float* w[9]; const float* b[9];
    float*       dst[9];
    int cout[9], npx[9], obase[9], bstart[9], npxb[9];
};

__launch_bounds__(256)
__global__ void det1x1_fused(Det9 d)
{
    int bid = blockIdx.x;
    int q = 0;
#pragma unroll
    for (int i = 1; i < 9; ++i) if (bid >= d.bstart[i]) q = i;
    int local = bid - d.bstart[q];
    int coIdx = local / d.npxb[q];
    int pxIdx = local - coIdx * d.npxb[q];
    const float* in = d.src[q];
    const float* w  = d.w[q];
    const float* b  = d.b[q];
    float* out = d.dst[q];
    int Cout = d.cout[q], NPX = d.npx[q], outBase = d.obase[q];

    __shared__ float s_in[16][64];
    __shared__ float s_w[16][64];
    int t = threadIdx.x;
    int pxg = t & 31, cg = t >> 5;
    int px0 = pxIdx * 64;
    int co0 = coIdx * 64;
    float acc[8][2];
#pragma unroll
    for (int c = 0; c < 8; ++c) { acc[c][0] = 0.f; acc[c][1] = 0.f; }
    int wco = t >> 2, wpart = t & 3;
    for (int ch = 0; ch < 16; ++ch) {
        int ci0 = ch << 4;
#pragma unroll
        for (int k = 0; k < 4; ++k) {
            int id = t + k * 256;
            int ci = id >> 6, pp = id & 63;
            int gp = px0 + pp;
            s_in[ci][pp] = (gp < NPX) ? in[(size_t)(ci0 + ci) * NPX + gp] : 0.f;
        }
        {
            int gco = co0 + wco;
            if (gco < Cout) {
                const float* run = w + (size_t)gco * 256 + ci0;
#pragma unroll
                for (int k = 0; k < 4; ++k) {
                    int e = wpart + 4 * k;
                    s_w[e][wco] = run[e];
                }
            } else {
#pragma unroll
                for (int k = 0; k < 4; ++k) s_w[wpart + 4 * k][wco] = 0.f;
            }
        }
        __syncthreads();
#pragma unroll
        for (int ci = 0; ci < 16; ++ci) {
            float i0 = s_in[ci][pxg * 2], i1 = s_in[ci][pxg * 2 + 1];
#pragma unroll
            for (int c = 0; c < 8; ++c) {
                float wv = s_w[ci][cg * 8 + c];
                acc[c][0] += wv * i0;
                acc[c][1] += wv * i1;
            }
        }
        __syncthreads();
    }
    for (int c = 0; c < 8; ++c) {
        int co = co0 + cg * 8 + c;
        if (co >= Cout) break;
        float bb = b[co];
#pragma unroll
        for (int j = 0; j < 2; ++j) {
            int p = px0 + pxg * 2 + j;
            if (p < NPX) out[(size_t)co * 8400 + outBase + p] = acc[c][j] + bb;
        }
    }
}

// ---------------- conv 3x3 body (shared by smooth + fused heads) ----------------
// INW = TW+3 (odd stride -> read banks <=2-way = free) and keeps LDS below the
// 5-blocks/CU threshold (30.6KB) so the 1136-block head grid fits in ONE
// occupancy wave (round-5 ran two: 26% avg occupancy).
template<int TW, int TH, int TCO>
__device__ __forceinline__ void conv3x3_body(
    const float* __restrict__ src, const float* __restrict__ w,
    const float* __restrict__ bias, float* __restrict__ dst,
    int H, int W, int act, int bx0, int by0, int co0,
    float* __restrict__ sin0, float* __restrict__ sin1,
    float* __restrict__ sw0, float* __restrict__ sw1)
{
    constexpr int TPX  = TW * TH;
    constexpr int NXQ  = TW / 4;
    constexpr int PXGN = TPX / 4;
    constexpr int COG  = 256 / PXGN;
    constexpr int COPT = TCO / COG;
    constexpr int INW  = TW + 3;
    constexpr int INH  = TH + 2;
    constexpr int SW   = TW + 2;
    constexpr int INSLOTS = 8 * INH * SW;
    constexpr int KSTG = (INSLOTS + 255) / 256;
    constexpr int EPT  = 72 * TCO / 256;      // 9 for TCO=32

    int t = threadIdx.x;
    int pxg = t % PXGN, cg = t / PXGN;
    int xq = pxg % NXQ, yr = pxg / NXQ;
    int x0 = xq * 4;
    int HW = H * W;

    // ch-invariant staging descriptors
    int sl[KSTG], sg[KSTG];
#pragma unroll
    for (int k = 0; k < KSTG; ++k) {
        int id = t + k * 256;
        sl[k] = -1; sg[k] = -1;
        if (id < INSLOTS) {
            int ci = id / (INH * SW);
            int rem = id - ci * (INH * SW);
            int r = rem / SW, cc = rem - r * SW;
            sl[k] = (ci * INH + r) * INW + cc;
            int gy = by0 - 1 + r, gx = bx0 - 1 + cc;
            if (gy >= 0 && gy < H && gx >= 0 && gx < W)
                sg[k] = ci * HW + gy * W + gx;
        }
    }
    int wco = t % TCO;          // lanes -> distinct banks on LDS weight writes
    int wpart = t / TCO;
    const float* wbase = w + (size_t)(co0 + wco) * 2304;

    float acc[COPT][4];
#pragma unroll
    for (int c = 0; c < COPT; ++c)
#pragma unroll
        for (int i = 0; i < 4; ++i) acc[c][i] = 0.f;

    // stage chunk 0 directly
    {
#pragma unroll
        for (int k = 0; k < KSTG; ++k)
            if (sl[k] >= 0) sin0[sl[k]] = (sg[k] >= 0) ? src[sg[k]] : 0.f;
#pragma unroll
        for (int k = 0; k < EPT; ++k) {
            int e = wpart * EPT + k;
            sw0[e * TCO + wco] = wbase[e];
        }
    }
    __syncthreads();

    for (int ch = 0; ch < 32; ++ch) {
        float* cin = (ch & 1) ? sin1 : sin0;
        float* cw  = (ch & 1) ? sw1  : sw0;
        float vin[KSTG]; float vw[EPT];
        bool pf = (ch < 31);
        if (pf) {
            const float* sb = src + (size_t)((ch + 1) * 8) * HW;
            const float* wr = wbase + (ch + 1) * 72;
#pragma unroll
            for (int k = 0; k < KSTG; ++k)
                vin[k] = (sg[k] >= 0) ? sb[sg[k]] : 0.f;
#pragma unroll
            for (int k = 0; k < EPT; ++k)
                vw[k] = wr[wpart * EPT + k];
        }
        // compute chunk ch
        for (int ci = 0; ci < 8; ++ci) {
            float inr[3][6];
#pragma unroll
            for (int ky = 0; ky < 3; ++ky)
#pragma unroll
                for (int j = 0; j < 6; ++j)
                    inr[ky][j] = cin[(ci * INH + yr + ky) * INW + x0 + j];
            const float* wrow = cw + ci * 9 * TCO;
#pragma unroll
            for (int ky = 0; ky < 3; ++ky) {
#pragma unroll
                for (int kx = 0; kx < 3; ++kx) {
#pragma unroll
                    for (int c = 0; c < COPT; ++c) {
                        float wv = wrow[(ky * 3 + kx) * TCO + cg * COPT + c];
#pragma unroll
                        for (int i = 0; i < 4; ++i)
                            acc[c][i] += wv * inr[ky][kx + i];
                    }
                }
            }
        }
        if (pf) {
            float* nin = (ch & 1) ? sin0 : sin1;
            float* nw  = (ch & 1) ? sw0  : sw1;
#pragma unroll
            for (int k = 0; k < KSTG; ++k)
                if (sl[k] >= 0) nin[sl[k]] = vin[k];
#pragma unroll
            for (int k = 0; k < EPT; ++k) {
                int e = wpart * EPT + k;
                nw[e * TCO + wco] = vw[k];
            }
        }
        __syncthreads();
    }

    int y = by0 + yr;
#pragma unroll
    for (int c = 0; c < COPT; ++c) {
        int co = co0 + cg * COPT + c;
        float bb = bias[co];
#pragma unroll
        for (int i = 0; i < 4; ++i) {
            int x = bx0 + x0 + i;
            if (x < W && y < H) {
                float v = acc[c][i] + bb;
                if (act) v = (v >= 0.f) ? v : 0.1f * v;
                dst[(size_t)co * HW + y * W + x] = v;
            }
        }
    }
}

// ---------------- smooth conv wrapper (single level) ----------------
template<int TW, int TH, int TCO>
__launch_bounds__(256)
__global__ void conv3x3_t(const float* __restrict__ src, const float* __restrict__ w,
                          const float* __restrict__ b, float* __restrict__ dst,
                          int H, int W, int act)
{
    constexpr int INW = TW + 3, INH = TH + 2;
    __shared__ float s_in[2][8 * INH * INW];
    __shared__ float s_w[2][72 * TCO];
    int nTx = (W + TW - 1) / TW;
    int tx = blockIdx.x % nTx, ty = blockIdx.x / nTx;
    conv3x3_body<TW, TH, TCO>(src, w, b, dst, H, W, act,
                              tx * TW, ty * TH, blockIdx.y * TCO,
                              s_in[0], s_in[1], s_w[0], s_w[1]);
}

// ---------------- fused 3-level head conv (one layer, both branches) ----------------
struct HeadPtrs {
    const float* src[2][3];
    float*       dst[2][3];
};

__launch_bounds__(256)
__global__ void conv3x3_heads(HeadPtrs hp, const float* __restrict__ wA,
                              const float* __restrict__ wB,
                              const float* __restrict__ bA, const float* __restrict__ bB)
{
    constexpr int TW = 16, TH = 8, TCO = 32;
    constexpr int INW = TW + 3, INH = TH + 2;
    __shared__ float s_in[2][8 * INH * INW];
    __shared__ float s_w[2][72 * TCO];

    int tb = blockIdx.x;                       // 0..70: 50 (L3) + 15 (L4) + 6 (L5)
    int lvl = (tb < 50) ? 0 : (tb < 65) ? 1 : 2;
    int tloc = tb - ((lvl == 0) ? 0 : (lvl == 1) ? 50 : 65);
    int W = (lvl == 0) ? 80 : (lvl == 1) ? 40 : 20;
    int br = blockIdx.z;
    const float* src = hp.src[br][lvl];
    float* dst = hp.dst[br][lvl];
    const float* w    = br ? wB : wA;
    const float* bias = br ? bB : bA;
    int nTx = (W + TW - 1) / TW;
    int tx = tloc % nTx, ty = tloc / nTx;
    conv3x3_body<TW, TH, TCO>(src, w, bias, dst, W, W, 1,
                              tx * TW, ty * TH, blockIdx.y * TCO,
                              s_in[0], s_in[1], s_w[0], s_w[1]);
}

// ---------------- decode: scores, argmax, boxes, sort keys ----------------
__launch_bounds__(256)
__global__ void decode_kernel(const float* __restrict__ cls, const float* __restrict__ reg,
                              const float* __restrict__ ctn, float* __restrict__ out,
                              unsigned long long* __restrict__ keys)
{
    int p = blockIdx.x * 256 + threadIdx.x;
    if (p >= 16384) return;
    if (p >= 8400) { keys[p] = ~0ull; return; }
    int base, hs; float s;
    if (p < 6400)      { base = 0;    hs = 80; s = 8.f;  }
    else if (p < 8000) { base = 6400; hs = 40; s = 16.f; }
    else               { base = 8000; hs = 20; s = 32.f; }
    int local = p - base;
    float gx = (float)(local % hs), gy = (float)(local / hs);
    float ct = ctn[p];
    float sct = 1.f / (1.f + expf(-ct));
    float best = -1.f; int arg = 0;
    for (int c = 0; c < 80; ++c) {
        float v = cls[(size_t)c * 8400 + p];
        float sv = 1.f / (1.f + expf(-v));
        float sc = sqrtf(sv * sct);
        if (sc > best) { best = sc; arg = c; }
    }
    float r0 = reg[0 * 8400 + p], r1 = reg[1 * 8400 + p];
    float r2 = reg[2 * 8400 + p], r3 = reg[3 * 8400 + p];
    float x1 = (gx - expf(r0)) * s / 640.f;
    float y1 = (gy - expf(r1)) * s / 640.f;
    float x2 = (gx + expf(r2)) * s / 640.f;
    float y2 = (gy + expf(r3)) * s / 640.f;
    x1 = fminf(fmaxf(x1, 0.f), 1.f);
    y1 = fminf(fmaxf(y1, 0.f), 1.f);
    x2 = fminf(fmaxf(x2, 0.f), 1.f);
    y2 = fminf(fmaxf(y2, 0.f), 1.f);
    out[p * 4 + 0] = x1; out[p * 4 + 1] = y1;
    out[p * 4 + 2] = x2; out[p * 4 + 3] = y2;
    out[33600 + p] = best;
    out[42000 + p] = (float)arg;
    out[50400 + p] = 0.f;
    unsigned int ub = __float_as_uint(best);
    keys[p] = ((unsigned long long)(~ub) << 32) | (unsigned int)p;
}

// ---------------- hybrid bitonic sort of 16384 u64 keys ----------------
__launch_bounds__(256)
__global__ void bitonic_local(unsigned long long* __restrict__ keys, unsigned kmerge)
{
    __shared__ unsigned long long sk[2048];
    int t = threadIdx.x;
    unsigned base = blockIdx.x * 2048u;
#pragma unroll
    for (int m = 0; m < 8; ++m) sk[t + m * 256] = keys[base + t + m * 256];
    __syncthreads();
    if (kmerge == 0u) {
        for (unsigned k = 2; k <= 2048u; k <<= 1) {
            for (unsigned j = k >> 1; j > 0; j >>= 1) {
#pragma unroll
                for (int pp = 0; pp < 4; ++pp) {
                    unsigned p = (unsigned)t + pp * 256u;
                    unsigned li = ((p & ~(j - 1)) << 1) | (p & (j - 1));
                    unsigned gi = base + li;
                    bool up = ((gi & k) == 0);
                    unsigned long long a = sk[li], b = sk[li + j];
                    if ((a > b) == up) { sk[li] = b; sk[li + j] = a; }
                }
                __syncthreads();
            }
        }
    } else {
        unsigned k = kmerge;
        for (unsigned j = 1024; j > 0; j >>= 1) {
#pragma unroll
            for (int pp = 0; pp < 4; ++pp) {
                unsigned p = (unsigned)t + pp * 256u;
                unsigned li = ((p & ~(j - 1)) << 1) | (p & (j - 1));
                unsigned gi = base + li;
                bool up = ((gi & k) == 0);
                unsigned long long a = sk[li], b = sk[li + j];
                if ((a > b) == up) { sk[li] = b; sk[li + j] = a; }
            }
            __syncthreads();
        }
    }
#pragma unroll
    for (int m = 0; m < 8; ++m) keys[base + t + m * 256] = sk[t + m * 256];
}

__launch_bounds__(256)
__global__ void bitonic_global(unsigned long long* __restrict__ keys, unsigned k, unsigned j)
{
    unsigned p = blockIdx.x * 256u + threadIdx.x;
    unsigned i = ((p & ~(j - 1)) << 1) | (p & (j - 1));
    bool up = ((i & k) == 0);
    unsigned long long a = keys[i], b = keys[i + j];
    if ((a > b) == up) { keys[i] = b; keys[i + j] = a; }
}

// ---------------- expand sorted keys into SoA arrays ----------------
__launch_bounds__(256)
__global__ void sorted_aux(const unsigned long long* __restrict__ keys,
                           const float* __restrict__ out,
                           float* __restrict__ scs, int* __restrict__ clss,
                           int* __restrict__ idxs)
{
    int i = blockIdx.x * 256 + threadIdx.x;
    if (i >= 16384) return;
    unsigned long long key = keys[i];
    unsigned ub = ~(unsigned)(key >> 32);
    float sc = __uint_as_float(ub);
    unsigned idx = (unsigned)(key & 0xffffffffu);
    int cl = -1;
    if (idx < 8400u) cl = (int)out[42000 + idx];
    else sc = 0.f;
    scs[i] = sc; clss[i] = cl; idxs[i] = (int)idx;
}

// ---------------- NMS stage 1: per-class stable compaction ----------------
__launch_bounds__(256)
__global__ void compact_cls(const float* __restrict__ scs, const int* __restrict__ clss,
                            const int* __restrict__ idxs, const float* __restrict__ outbuf,
                            float* __restrict__ GX1, float* __restrict__ GY1,
                            float* __restrict__ GX2, float* __restrict__ GY2,
                            float* __restrict__ GAR, int* __restrict__ GIX,
                            int* __restrict__ NCOUNT, int* __restrict__ NBASE)
{
    int c = blockIdx.x, t = threadIdx.x;
    __shared__ int s_red[2];
    __shared__ int s_wtot[4];
    int cb = 0, co = 0;
    for (int i = t; i < 16384; i += 256) {
        float sc = scs[i]; int cl = clss[i];
        if (sc >= CONF_T && cl >= 0) { cb += (cl < c); co += (cl == c); }
    }
    if (t == 0) { s_red[0] = 0; s_red[1] = 0; }
    __syncthreads();
    atomicAdd(&s_red[0], cb);
    atomicAdd(&s_red[1], co);
    __syncthreads();
    int base = s_red[0], n = s_red[1];
    if (t == 0) { NCOUNT[c] = n; NBASE[c] = base; }

    int rank = 0;
    for (int st = 0; st < 16384; st += 256) {
        int i = st + t;
        float sc = scs[i]; int cl = clss[i];
        bool flag = (sc >= CONF_T && cl == c);
        unsigned long long m = __ballot(flag);
        int lane = t & 63, wv = t >> 6;
        if (lane == 0) s_wtot[wv] = __popcll(m);
        __syncthreads();
        int off = rank;
        for (int w = 0; w < wv; ++w) off += s_wtot[w];
        int tot = s_wtot[0] + s_wtot[1] + s_wtot[2] + s_wtot[3];
        if (flag) {
            int pos = off + __popcll(m & ((1ull << lane) - 1ull));
            int idx = idxs[i];
            float x1 = outbuf[idx * 4 + 0], y1 = outbuf[idx * 4 + 1];
            float x2 = outbuf[idx * 4 + 2], y2 = outbuf[idx * 4 + 3];
            GX1[base + pos] = x1; GY1[base + pos] = y1;
            GX2[base + pos] = x2; GY2[base + pos] = y2;
            GAR[base + pos] = (x2 - x1) * (y2 - y1);
            GIX[base + pos] = idx;
        }
        rank += tot;
        __syncthreads();
    }
}

// ---------------- NMS stage 2: suppression bit-matrix (parallel) ----------------
__launch_bounds__(256)
__global__ void nms_mask(const float* __restrict__ GX1, const float* __restrict__ GY1,
                         const float* __restrict__ GX2, const float* __restrict__ GY2,
                         const float* __restrict__ GAR,
                         const int* __restrict__ NCOUNT, const int* __restrict__ NBASE,
                         unsigned long long* __restrict__ MASK)
{
    int c = blockIdx.y;
    int n = NCOUNT[c];
    if ((int)(blockIdx.x * 256) >= n) return;
    int base = NBASE[c];
    int t = threadIdx.x;
    int r = blockIdx.x * 256 + t;
    bool hav = (r < n);
    float rx1 = 0.f, ry1 = 0.f, rx2 = 0.f, ry2 = 0.f, rar = 0.f;
    if (hav) {
        rx1 = GX1[base + r]; ry1 = GY1[base + r];
        rx2 = GX2[base + r]; ry2 = GY2[base + r];
        rar = GAR[base + r];
    }
    __shared__ float tx1[2048], ty1[2048], tx2[2048], ty2[2048], tar[2048];
    for (int jt = 0; jt < n; jt += 2048) {
        int cnt = min(2048, n - jt);
        __syncthreads();
        for (int k = t; k < cnt; k += 256) {
            tx1[k] = GX1[base + jt + k]; ty1[k] = GY1[base + jt + k];
            tx2[k] = GX2[base + jt + k]; ty2[k] = GY2[base + jt + k];
            tar[k] = GAR[base + jt + k];
        }
        __syncthreads();
        if (hav) {
            int w0 = jt >> 6;
            int nw = (cnt + 63) >> 6;
            for (int w = 0; w < nw; ++w) {
                int jb = jt + w * 64;
                unsigned long long bits = 0ull;
                if (jb + 63 > r) {
                    int kmax = min(64, n - jb);
                    for (int kk = 0; kk < kmax; ++kk) {
                        int j = jb + kk;
                        if (j > r) {
                            int k2 = j - jt;
                            float xx1 = fmaxf(rx1, tx1[k2]);
                            float yy1 = fmaxf(ry1, ty1[k2]);
                            float xx2 = fminf(rx2, tx2[k2]);
                            float yy2 = fminf(ry2, ty2[k2]);
                            float ww = fmaxf(1e-28f, xx2 - xx1);
                            float hh = fmaxf(1e-28f, yy2 - yy1);
                            float inter = ww * hh;
                            float ovr = inter / (rar + tar[k2] - inter);
                            if (ovr > NMS_T) bits |= (1ull << kk);
                        }
                    }
                }
                MASK[(size_t)(base + r) * WMAX + w0 + w] = bits;
            }
        }
    }
}

// ---------------- NMS stage 3: chunked bitmask scan (80 blocks) ----------------
__launch_bounds__(256)
__global__ void nms_scan(const unsigned long long* __restrict__ MASK,
                         const int* __restrict__ GIX,
                         const int* __restrict__ NCOUNT, const int* __restrict__ NBASE,
                         float* __restrict__ keep)
{
    int c = blockIdx.x, t = threadIdx.x;
    int n = NCOUNT[c];
    if (n == 0) return;
    int base = NBASE[c];
    int Wc = (n + 63) >> 6;
    __shared__ unsigned long long remv[WMAX];
    __shared__ unsigned long long sld[32][WMAX];
    __shared__ unsigned int s_alive;
    for (int w = t; w < Wc; w += 256) remv[w] = 0ull;
    __syncthreads();
    for (int i0 = 0; i0 < n; i0 += 32) {
        int rows = min(32, n - i0);
        int tot = rows * Wc;
        for (int k = t; k < tot; k += 256) {
            int rr = k / Wc, w = k - rr * Wc;
            sld[rr][w] = MASK[(size_t)(base + i0 + rr) * WMAX + w];
        }
        __syncthreads();
        if (t == 0) {
            int wq = i0 >> 6, b0 = i0 & 63;
            unsigned long long lw = remv[wq];
            unsigned am = 0;
            for (int rr = 0; rr < rows; ++rr) {
                if (!((lw >> (b0 + rr)) & 1ull)) {
                    am |= (1u << rr);
                    lw |= sld[rr][wq];
                }
            }
            s_alive = am;
        }
        __syncthreads();
        unsigned am = s_alive;
        for (int w = t; w < Wc; w += 256) {
            unsigned long long acc = remv[w];
            unsigned m = am;
            while (m) { int rr = __ffs(m) - 1; m &= m - 1; acc |= sld[rr][w]; }
            remv[w] = acc;
        }
        if (t < rows && ((am >> t) & 1u)) keep[GIX[base + i0 + t]] = 1.0f;
        __syncthreads();
    }
}

// ---------------- host orchestration ----------------
extern "C" void kernel_launch(void* const* d_in, const int* in_sizes, int n_in,
                              void* d_out, int out_size, void* d_ws, size_t ws_size,
                              hipStream_t stream)
{
    const float* c3      = (const float*)d_in[0];
    const float* c4      = (const float*)d_in[1];
    const float* c5      = (const float*)d_in[2];
    const float* lat1_w  = (const float*)d_in[3];
    const float* lat1_b  = (const float*)d_in[4];
    const float* lat2_w  = (const float*)d_in[5];
    const float* lat2_b  = (const float*)d_in[6];
    const float* lat3_w  = (const float*)d_in[7];
    const float* lat3_b  = (const float*)d_in[8];
    const float* sm1_w   = (const float*)d_in[9];
    const float* sm1_b   = (const float*)d_in[10];
    const float* sm2_w   = (const float*)d_in[11];
    const float* sm2_b   = (const float*)d_in[12];
    const float* sm3_w   = (const float*)d_in[13];
    const float* sm3_b   = (const float*)d_in[14];
    const float* clsh_w  = (const float*)d_in[15];
    const float* clsh_b  = (const float*)d_in[16];
    const float* regh_w  = (const float*)d_in[17];
    const float* regh_b  = (const float*)d_in[18];
    const float* clsd_w  = (const float*)d_in[19];
    const float* clsd_b  = (const float*)d_in[20];
    const float* regd_w  = (const float*)d_in[21];
    const float* regd_b  = (const float*)d_in[22];
    const float* ctnd_w  = (const float*)d_in[23];
    const float* ctnd_b  = (const float*)d_in[24];

    float* ws = (float*)d_ws;
    float* T3 = ws + OFF_T3;  float* T4 = ws + OFF_T4;  float* T5 = ws + OFF_T5;
    float* P3 = ws + OFF_P3;  float* P4 = ws + OFF_P4;  float* P5 = ws + OFF_P5;
    float* HA3 = ws + OFF_HA3; float* HA4 = ws + OFF_HA4; float* HA5 = ws + OFF_HA5;
    float* HB3 = ws + OFF_HB3; float* HB4 = ws + OFF_HB4; float* HB5 = ws + OFF_HB5;
    float* HD3 = ws + OFF_HD3; float* HD4 = ws + OFF_HD4; float* HD5 = ws + OFF_HD5;
    float* CLS = ws + OFF_CLS; float* REG = ws + OFF_REG; float* CTN = ws + OFF_CTN;
    unsigned long long* KEYS = (unsigned long long*)(ws + POFF_KEYS);
    float* SCS = ws + POFF_SCS;
    int* CLSS = (int*)(ws + POFF_CLSS);
    int* IDXS = (int*)(ws + POFF_IDXS);
    float* GX1 = ws + POFF_GX1; float* GY1 = ws + POFF_GY1;
    float* GX2 = ws + POFF_GX2; float* GY2 = ws + POFF_GY2;
    float* GAR = ws + POFF_GAR;
    int* GIX = (int*)(ws + POFF_GIX);
    int* NCOUNT = (int*)(ws + POFF_NCNT);
    int* NBASE  = (int*)(ws + POFF_NBASE);
    unsigned long long* MASK = (unsigned long long*)(ws + POFF_MASK);

    float* out = (float*)d_out;
    dim3 blk(256);
    const size_t WSTEP = 256u * 256u * 9u;

    // ---- FPN ----
    conv1x1_kernel<<<dim3(7, 4), blk, 0, stream>>>(c5, lat3_w, lat3_b, T5, nullptr,
                                                   512, 256, 400, 20, 400, 0);
    conv3x3_t<8, 4, 32><<<dim3(15, 8), blk, 0, stream>>>(T5, sm3_w, sm3_b, P5, 20, 20, 0);
    conv1x1_kernel<<<dim3(25, 4), blk, 0, stream>>>(c4, lat2_w, lat2_b, T4, T5,
                                                    256, 256, 1600, 40, 1600, 0);
    conv3x3_t<16, 4, 32><<<dim3(30, 8), blk, 0, stream>>>(T4, sm2_w, sm2_b, P4, 40, 40, 0);
    conv1x1_kernel<<<dim3(100, 4), blk, 0, stream>>>(c3, lat1_w, lat1_b, T3, T4,
                                                     128, 256, 6400, 80, 6400, 0);
    conv3x3_t<16, 8, 32><<<dim3(50, 8), blk, 0, stream>>>(T3, sm1_w, sm1_b, P3, 80, 80, 0);

    // ---- heads: 4 fused layers, 3 levels + both branches per dispatch ----
    {
        float* clsS[3][5] = { {P3, HA3, HB3, HA3, HB3},
                              {P4, HA4, HB4, HA4, HB4},
                              {P5, HA5, HB5, HA5, HB5} };
        float* regS[3][5] = { {P3, T3,  HD3, T3,  HD3},
                              {P4, T4,  HD4, T4,  HD4},
                              {P5, T5,  HD5, T5,  HD5} };
        for (int i = 0; i < 4; ++i) {
            HeadPtrs hp;
            for (int l = 0; l < 3; ++l) {
                hp.src[0][l] = clsS[l][i];     hp.dst[0][l] = clsS[l][i + 1];
                hp.src[1][l] = regS[l][i];     hp.dst[1][l] = regS[l][i + 1];
            }
            conv3x3_heads<<<dim3(71, 8, 2), blk, 0, stream>>>(
                hp, clsh_w + (size_t)i * WSTEP, regh_w + (size_t)i * WSTEP,
                clsh_b + i * 256, regh_b + i * 256);
        }
    }

    // ---- detectors: all 9 (level x {cls,reg,ctn}) in one dispatch ----
    {
        Det9 d;
        const float* feats[3][2] = { {HB3, HD3}, {HB4, HD4}, {HB5, HD5} };
        int   npx[3]   = {6400, 1600, 400};
        int   obase[3] = {0, 6400, 8000};
        int q = 0, bacc = 0;
        for (int l = 0; l < 3; ++l) {
            // cls
            d.src[q] = feats[l][0]; d.w[q] = clsd_w; d.b[q] = clsd_b; d.dst[q] = CLS;
            d.cout[q] = 80; d.npx[q] = npx[l]; d.obase[q] = obase[l];
            d.bstart[q] = bacc; d.npxb[q] = (npx[l] + 63) / 64;
            bacc += d.npxb[q] * 2; ++q;
            // reg
            d.src[q] = feats[l][1]; d.w[q] = regd_w; d.b[q] = regd_b; d.dst[q] = REG;
            d.cout[q] = 4; d.npx[q] = npx[l]; d.obase[q] = obase[l];
            d.bstart[q] = bacc; d.npxb[q] = (npx[l] + 63) / 64;
            bacc += d.npxb[q]; ++q;
            // ctn
            d.src[q] = feats[l][1]; d.w[q] = ctnd_w; d.b[q] = ctnd_b; d.dst[q] = CTN;
            d.cout[q] = 1; d.npx[q] = npx[l]; d.obase[q] = obase[l];
            d.bstart[q] = bacc; d.npxb[q] = (npx[l] + 63) / 64;
            bacc += d.npxb[q]; ++q;
        }
        det1x1_fused<<<dim3(bacc), blk, 0, stream>>>(d);
    }

    // ---- decode ----
    decode_kernel<<<dim3(64), blk, 0, stream>>>(CLS, REG, CTN, out, KEYS);

    // ---- hybrid bitonic sort ----
    bitonic_local<<<dim3(8), blk, 0, stream>>>(KEYS, 0u);
    bitonic_global<<<dim3(32), blk, 0, stream>>>(KEYS, 4096u, 2048u);
    bitonic_local<<<dim3(8), blk, 0, stream>>>(KEYS, 4096u);
    bitonic_global<<<dim3(32), blk, 0, stream>>>(KEYS, 8192u, 4096u);
    bitonic_global<<<dim3(32), blk, 0, stream>>>(KEYS, 8192u, 2048u);
    bitonic_local<<<dim3(8), blk, 0, stream>>>(KEYS, 8192u);
    bitonic_global<<<dim3(32), blk, 0, stream>>>(KEYS, 16384u, 8192u);
    bitonic_global<<<dim3(32), blk, 0, stream>>>(KEYS, 16384u, 4096u);
    bitonic_global<<<dim3(32), blk, 0, stream>>>(KEYS, 16384u, 2048u);
    bitonic_local<<<dim3(8), blk, 0, stream>>>(KEYS, 16384u);

    // ---- NMS pipeline ----
    sorted_aux<<<dim3(64), blk, 0, stream>>>(KEYS, out, SCS, CLSS, IDXS);
    compact_cls<<<dim3(80), blk, 0, stream>>>(SCS, CLSS, IDXS, out,
                                              GX1, GY1, GX2, GY2, GAR, GIX, NCOUNT, NBASE);
    nms_mask<<<dim3(33, 80), blk, 0, stream>>>(GX1, GY1, GX2, GY2, GAR, NCOUNT, NBASE, MASK);
    nms_scan<<<dim3(80), blk, 0, stream>>>(MASK, GIX, NCOUNT, NBASE, out + 50400);
}